// Round 2
// baseline (1161.678 us; speedup 1.0000x reference)
//
#include <hip/hip_runtime.h>
#include <cstdint>
#include <cstddef>

typedef __attribute__((ext_vector_type(8))) short short8;
typedef __attribute__((ext_vector_type(4))) short short4v;
typedef __attribute__((ext_vector_type(4))) float float4v;

#define DEV static __device__ __forceinline__

DEV float b2f(unsigned short u) { return __uint_as_float(((unsigned int)u) << 16); }
DEV unsigned short f2b(float f) {
  unsigned int u = __float_as_uint(f);
  u = (u + 0x7fffu + ((u >> 16) & 1u)) >> 16;
  return (unsigned short)u;
}

// ---- problem sizes ----
static constexpr int NP = 12416;   // padded fused-N: 8192 qkv + 4096 z + 32 a + 32 b + 64 pad

// ---- ws layout (bytes), lifetime-overlaid; peak ~162.5 MB ----
static constexpr size_t OFF_QKVZ = 0;                         // bf16 [4096][12416], live GEMM1->rms_silu
static constexpr size_t SZ_QKVZ  = (size_t)4096*12416*2;      // 101,711,872
static constexpr size_t OFF_XB   = SZ_QKVZ;                   // bf16 x [4096][2048], live cast->GEMM1
static constexpr size_t SZ_XB    = (size_t)4096*2048*2;       // 16,777,216
static constexpr size_t OFF_WCAT = OFF_XB + SZ_XB;            // bf16 [12416][2048], live prep->GEMM1
static constexpr size_t SZ_WCAT  = (size_t)NP*2048*2;         // 50,855,936  -> end 169,345,024
static constexpr size_t OFF_QKVS = OFF_XB;                    // bf16 [4096][8192], overlays xb+wcat (dead after GEMM1)
static constexpr size_t SZ_QKVS  = (size_t)4096*8192*2;       // 67,108,864  -> end 168,820,736 (fits)
static constexpr size_t OFF_YN   = OFF_XB;                    // bf16 [4096][4096], after scan (qkvs dead)
static constexpr size_t SZ_YN    = (size_t)4096*4096*2;       // 33,554,432
static constexpr size_t OFF_WOB  = OFF_YN + SZ_YN;            // bf16 Wout [2048][4096], after scan
static constexpr size_t SZ_WOB   = (size_t)2048*4096*2;       // -> end 152,043,520 (fits under 168.8M)
static constexpr size_t OFF_G    = OFF_WCAT + SZ_WCAT;        // f32 [4096][32]
static constexpr size_t OFF_BET  = OFF_G + (size_t)4096*32*4;
static constexpr size_t WS_NEED  = OFF_BET + (size_t)4096*32*4;  // 170,393,600 (~162.5 MiB)

// ---- helpers ----
DEV void gl16(const unsigned short* g, unsigned short* l) {
  __builtin_amdgcn_global_load_lds((const __attribute__((address_space(1))) unsigned int*)g,
                                   (__attribute__((address_space(3))) unsigned int*)l,
                                   16, 0, 0);
}

DEV void store_out(unsigned short* C, size_t off, float v) { C[off] = f2b(v); }
DEV void store_out(float* C, size_t off, float v)          { C[off] = v; }

// ---- generic cast fp32 -> bf16 (n multiple of 4) ----
__global__ void castk(const float* __restrict__ in, unsigned short* __restrict__ out, int n4) {
  int idx = blockIdx.x * 256 + threadIdx.x;
  if (idx >= n4) return;
  float4v v = ((const float4v*)in)[idx];
  short4v o;
  o[0] = (short)f2b(v[0]); o[1] = (short)f2b(v[1]);
  o[2] = (short)f2b(v[2]); o[3] = (short)f2b(v[3]);
  ((short4v*)out)[idx] = o;
}

// ---- build concatenated weight [12416][2048] bf16 ----
__global__ void prep_wcat(const float* __restrict__ Wqkv, const float* __restrict__ Wz,
                          const float* __restrict__ Wa, const float* __restrict__ Wb,
                          unsigned short* __restrict__ Wcat) {
  size_t e4 = (size_t)blockIdx.x * 256 + threadIdx.x;
  if (e4 >= (size_t)NP * 2048 / 4) return;
  size_t e = e4 * 4;
  int row = (int)(e >> 11);
  int col = (int)(e & 2047);
  float4v v;
  if (row < 8192)       v = *(const float4v*)&Wqkv[(size_t)row * 2048 + col];
  else if (row < 12288) v = *(const float4v*)&Wz[(size_t)(row - 8192) * 2048 + col];
  else if (row < 12320) v = *(const float4v*)&Wa[(size_t)(row - 12288) * 2048 + col];
  else if (row < 12352) v = *(const float4v*)&Wb[(size_t)(row - 12320) * 2048 + col];
  else                  v = (float4v){0.f, 0.f, 0.f, 0.f};
  short4v o;
  o[0] = (short)f2b(v[0]); o[1] = (short)f2b(v[1]);
  o[2] = (short)f2b(v[2]); o[3] = (short)f2b(v[3]);
  *(short4v*)&Wcat[e] = o;
}

// ---- bf16 MFMA GEMM: C[M][N] = A[M][K] @ B[N][K]^T (m97 structure) ----
template <typename OutT>
__global__ __launch_bounds__(256)
void gemm_bt(const unsigned short* __restrict__ A, const unsigned short* __restrict__ B,
             OutT* __restrict__ C, int M, int N, int K) {
  __shared__ __align__(16) unsigned short lA[128 * 32];
  __shared__ __align__(16) unsigned short lB[128 * 32];
  const int t = threadIdx.x;
  const int bm = blockIdx.x, bn = blockIdx.y;
  const int wave = t >> 6, lane = t & 63;
  const int wm = (wave >> 1) * 64, wn = (wave & 1) * 64;
  const int l16 = lane & 15, lg = lane >> 4;

  const int srow = t >> 2, skof = (t & 3) * 8;
  const unsigned short* Ag = A + (size_t)(bm * 128 + srow) * K + skof;
  const unsigned short* Bg = B + (size_t)(bn * 128 + srow) * K + skof;
  unsigned short* lAp = &lA[srow * 32 + skof];
  unsigned short* lBp = &lB[srow * 32 + skof];

  float4v acc[4][4] = {};

  const int nk = K >> 5;
  for (int kt = 0; kt < nk; kt++) {
    const unsigned short* a0 = Ag + kt * 32;
    const unsigned short* b0 = Bg + kt * 32;
    gl16(a0, lAp);
    gl16(a0 + (size_t)64 * K, lAp + 64 * 32);
    gl16(b0, lBp);
    gl16(b0 + (size_t)64 * K, lBp + 64 * 32);
    __syncthreads();
    short8 av[4], bv[4];
#pragma unroll
    for (int i = 0; i < 4; i++) av[i] = *(const short8*)&lA[(wm + i * 16 + l16) * 32 + lg * 8];
#pragma unroll
    for (int j = 0; j < 4; j++) bv[j] = *(const short8*)&lB[(wn + j * 16 + l16) * 32 + lg * 8];
#pragma unroll
    for (int i = 0; i < 4; i++)
#pragma unroll
      for (int j = 0; j < 4; j++)
        acc[i][j] = __builtin_amdgcn_mfma_f32_16x16x32_bf16(av[i], bv[j], acc[i][j], 0, 0, 0);
    __syncthreads();
  }

#pragma unroll
  for (int i = 0; i < 4; i++) {
    int row0 = bm * 128 + wm + i * 16 + lg * 4;
#pragma unroll
    for (int j = 0; j < 4; j++) {
      int col = bn * 128 + wn + j * 16 + l16;
#pragma unroll
      for (int rr = 0; rr < 4; rr++) {
        store_out(C, (size_t)(row0 + rr) * N + col, acc[i][j][rr]);
      }
    }
  }
}

// ---- conv(KW=4) + silu + q/k L2-norm ----
__global__ __launch_bounds__(256)
void conv_silu_norm(const unsigned short* __restrict__ qkvz, const float* __restrict__ conv_w,
                    unsigned short* __restrict__ qkvs) {
  const int m = blockIdx.x;           // b*S + s
  const int sloc = m & 1023;
  const int t = threadIdx.x;
  const int c0 = t * 32;
  float out[32];
#pragma unroll
  for (int cc = 0; cc < 32; cc += 8) {
    const int c = c0 + cc;
    float a8[8] = {0.f, 0.f, 0.f, 0.f, 0.f, 0.f, 0.f, 0.f};
#pragma unroll
    for (int j = 0; j < 4; j++) {
      const int sj = sloc - 3 + j;
      if (sj >= 0) {
        short8 v8 = *(const short8*)&qkvz[(size_t)(m - 3 + j) * NP + c];
#pragma unroll
        for (int e = 0; e < 8; e++)
          a8[e] = fmaf(b2f((unsigned short)v8[e]), conv_w[(c + e) * 4 + j], a8[e]);
      }
    }
#pragma unroll
    for (int e = 0; e < 8; e++) { float x = a8[e]; out[cc + e] = x * (1.f / (1.f + expf(-x))); }
  }
  if (c0 < 4096) {  // q or k head: L2 normalize over 128 ch (4 threads/head)
    float ss = 0.f;
#pragma unroll
    for (int e = 0; e < 32; e++) ss += out[e] * out[e];
    ss += __shfl_xor(ss, 1);
    ss += __shfl_xor(ss, 2);
    float sc = rsqrtf(ss + 1e-6f);
    if (c0 < 2048) sc *= 0.08838834764831845f;  // * DK^-0.5 for q
#pragma unroll
    for (int e = 0; e < 32; e++) out[e] *= sc;
  }
  const size_t ob = (size_t)m * 8192 + c0;
#pragma unroll
  for (int cc = 0; cc < 32; cc += 8) {
    short8 w;
#pragma unroll
    for (int e = 0; e < 8; e++) w[e] = (short)f2b(out[cc + e]);
    *(short8*)&qkvs[ob + cc] = w;
  }
}

// ---- conv_state output: (B,CI,KW) fp32 from pre-conv qkv ----
__global__ void conv_state_k(const unsigned short* __restrict__ qkvz, float* __restrict__ cs) {
  int idx = blockIdx.x * 256 + threadIdx.x;  // < 131072 = 4*8192*4
  int b = idx >> 15;
  int rem = idx & 32767;
  int c = rem >> 2;
  int j = rem & 3;
  cs[idx] = b2f(qkvz[(size_t)(b * 1024 + 1020 + j) * NP + c]);
}

// ---- g / beta from a,b columns ----
__global__ void gb_kernel(const unsigned short* __restrict__ qkvz, const float* __restrict__ A_log,
                          const float* __restrict__ dt_bias, float* __restrict__ g,
                          float* __restrict__ bet) {
  int idx = blockIdx.x * 256 + threadIdx.x;  // < 4096*64
  int m = idx >> 6, n = idx & 63;
  if (n < 32) {
    float a = b2f(qkvz[(size_t)m * NP + 12288 + n]) + dt_bias[n];
    float sp = (a > 20.f) ? a : log1pf(expf(a));
    g[m * 32 + n] = -expf(A_log[n]) * sp;
  } else {
    int nn = n - 32;
    float bb = b2f(qkvz[(size_t)m * NP + 12320 + nn]);
    bet[m * 32 + nn] = 1.f / (1.f + expf(-bb));
  }
}

// ---- sequential delta-rule scan, rows (DV) independent ----
// grid 256 = (b, h, dv-half); 512 threads: 8 threads per v-row x 16 state floats
__global__ __launch_bounds__(512)
void scan_kernel(const unsigned short* __restrict__ qkvs, const float* __restrict__ g,
                 const float* __restrict__ bet, unsigned short* __restrict__ y,
                 float* __restrict__ state_out) {
  __shared__ float kch[32][128];
  __shared__ float qch[32][128];
  __shared__ float vch[32][64];
  __shared__ float gch[32];
  __shared__ float bch[32];
  __shared__ float obuf[32][64];
  const int bid = blockIdx.x;
  const int b = bid >> 6;
  const int h = (bid >> 1) & 31;
  const int half = bid & 1;
  const int hk = h >> 1;
  const int t = threadIdx.x;
  const int r = t >> 3, o = t & 7;
  float s[16];
#pragma unroll
  for (int j = 0; j < 16; j++) s[j] = 0.f;

  const int stg_step = t >> 4, stg16 = t & 15;

  for (int ch = 0; ch < 32; ch++) {
    const int s0 = ch << 5;
    {
      size_t row = (size_t)((b << 10) + s0 + stg_step) * 8192;
      short8 kv8 = *(const short8*)&qkvs[row + 2048 + hk * 128 + stg16 * 8];
      short8 qv8 = *(const short8*)&qkvs[row + hk * 128 + stg16 * 8];
#pragma unroll
      for (int e = 0; e < 8; e++) {
        kch[stg_step][stg16 * 8 + e] = b2f((unsigned short)kv8[e]);
        qch[stg_step][stg16 * 8 + e] = b2f((unsigned short)qv8[e]);
      }
      short4v vv4 = *(const short4v*)&qkvs[row + 4096 + h * 128 + half * 64 + stg16 * 4];
#pragma unroll
      for (int e = 0; e < 4; e++) vch[stg_step][stg16 * 4 + e] = b2f((unsigned short)vv4[e]);
      if (t < 32) gch[t] = expf(g[((b << 10) + s0 + t) * 32 + h]);
      else if (t < 64) bch[t - 32] = bet[((b << 10) + s0 + (t - 32)) * 32 + h];
    }
    __syncthreads();
#pragma unroll 1
    for (int i = 0; i < 32; i++) {
      float gam = gch[i], be = bch[i], vr = vch[i][r];
      float kk[16], qq[16];
      const float4v* kp = (const float4v*)&kch[i][o * 16];
      const float4v* qp = (const float4v*)&qch[i][o * 16];
#pragma unroll
      for (int w = 0; w < 4; w++) {
        *(float4v*)&kk[w * 4] = kp[w];
        *(float4v*)&qq[w * 4] = qp[w];
      }
      float p = 0.f;
#pragma unroll
      for (int j = 0; j < 16; j++) p += s[j] * kk[j];
      p += __shfl_xor(p, 1); p += __shfl_xor(p, 2); p += __shfl_xor(p, 4);
      float dl = be * (vr - gam * p);
      float op = 0.f;
#pragma unroll
      for (int j = 0; j < 16; j++) {
        s[j] = fmaf(gam, s[j], dl * kk[j]);
        op += s[j] * qq[j];
      }
      op += __shfl_xor(op, 1); op += __shfl_xor(op, 2); op += __shfl_xor(op, 4);
      if (o == 0) obuf[i][r] = op;
    }
    __syncthreads();
#pragma unroll
    for (int idx = t; idx < 2048; idx += 512) {
      int st = idx >> 6, vv = idx & 63;
      y[(size_t)((b << 10) + s0 + st) * 4096 + h * 128 + half * 64 + vv] = f2b(obuf[st][vv]);
    }
    __syncthreads();
  }
  float* sp = state_out + ((size_t)((b * 32 + h) * 128 + half * 64 + r)) * 128 + o * 16;
#pragma unroll
  for (int j = 0; j < 16; j++) sp[j] = s[j];
}

// ---- RMSNorm over DV * norm_w * silu(z) -> yn bf16 ----
__global__ __launch_bounds__(256)
void rms_silu(const unsigned short* __restrict__ y, const unsigned short* __restrict__ qkvz,
              const float* __restrict__ nw, unsigned short* __restrict__ yn) {
  int m = blockIdx.x;
  int t = threadIdx.x;
  int head = t >> 3, oct = t & 7;
  int vb = head * 128 + oct * 16;
  const unsigned short* yp = y + (size_t)m * 4096 + vb;
  float yy[16];
  short8 y0 = *(const short8*)yp, y1 = *(const short8*)(yp + 8);
#pragma unroll
  for (int e = 0; e < 8; e++) { yy[e] = b2f((unsigned short)y0[e]); yy[8 + e] = b2f((unsigned short)y1[e]); }
  float ss = 0.f;
#pragma unroll
  for (int e = 0; e < 16; e++) ss += yy[e] * yy[e];
  ss += __shfl_xor(ss, 1); ss += __shfl_xor(ss, 2); ss += __shfl_xor(ss, 4);
  float rinv = rsqrtf(ss * (1.f / 128.f) + 1e-6f);
  const unsigned short* zp = qkvz + (size_t)m * NP + 8192 + vb;
  short8 z0 = *(const short8*)zp, z1 = *(const short8*)(zp + 8);
  short8 o0, o1;
#pragma unroll
  for (int e = 0; e < 8; e++) {
    float z = b2f((unsigned short)z0[e]);
    float v = nw[oct * 16 + e] * yy[e] * rinv * (z / (1.f + expf(-z)));
    o0[e] = (short)f2b(v);
    z = b2f((unsigned short)z1[e]);
    v = nw[oct * 16 + 8 + e] * yy[8 + e] * rinv * (z / (1.f + expf(-z)));
    o1[e] = (short)f2b(v);
  }
  unsigned short* op = yn + (size_t)m * 4096 + vb;
  *(short8*)op = o0;
  *(short8*)(op + 8) = o1;
}

extern "C" void kernel_launch(void* const* d_in, const int* in_sizes, int n_in,
                              void* d_out, int out_size, void* d_ws, size_t ws_size,
                              hipStream_t stream) {
  if (ws_size < WS_NEED) return;  // guard: fail with clean absmax, not a fault

  const float* x     = (const float*)d_in[0];
  const float* Wqkv  = (const float*)d_in[1];
  const float* Wz    = (const float*)d_in[2];
  const float* Wa    = (const float*)d_in[3];
  const float* Wb    = (const float*)d_in[4];
  const float* convw = (const float*)d_in[5];
  const float* Alog  = (const float*)d_in[6];
  const float* dtb   = (const float*)d_in[7];
  const float* nw    = (const float*)d_in[8];
  const float* Wout  = (const float*)d_in[9];

  char* ws = (char*)d_ws;
  unsigned short* qkvz = (unsigned short*)(ws + OFF_QKVZ);
  unsigned short* xb   = (unsigned short*)(ws + OFF_XB);
  unsigned short* wcat = (unsigned short*)(ws + OFF_WCAT);
  unsigned short* qkvs = (unsigned short*)(ws + OFF_QKVS);
  unsigned short* ynb  = (unsigned short*)(ws + OFF_YN);
  unsigned short* wob  = (unsigned short*)(ws + OFF_WOB);
  float* gbuf          = (float*)(ws + OFF_G);
  float* bbuf          = (float*)(ws + OFF_BET);

  float* outp       = (float*)d_out;
  float* conv_state = outp + 8388608;             // B*S*H
  float* state      = outp + 8388608 + 131072;    // + B*CI*KW
  unsigned short* ybuf = (unsigned short*)d_out;  // y bf16 scratch over outp region (rewritten by gemm2)

  castk<<<8192, 256, 0, stream>>>(x, xb, 2097152);
  prep_wcat<<<24832, 256, 0, stream>>>(Wqkv, Wz, Wa, Wb, wcat);

  dim3 g1(32, 97);
  gemm_bt<unsigned short><<<g1, 256, 0, stream>>>(xb, wcat, qkvz, 4096, NP, 2048);

  conv_silu_norm<<<4096, 256, 0, stream>>>(qkvz, convw, qkvs);
  conv_state_k<<<512, 256, 0, stream>>>(qkvz, conv_state);
  gb_kernel<<<1024, 256, 0, stream>>>(qkvz, Alog, dtb, gbuf, bbuf);

  scan_kernel<<<256, 512, 0, stream>>>(qkvs, gbuf, bbuf, ybuf, state);

  rms_silu<<<4096, 256, 0, stream>>>(ybuf, qkvz, nw, ynb);
  castk<<<8192, 256, 0, stream>>>(Wout, wob, 2097152);

  dim3 g2(32, 16);
  gemm_bt<float><<<g2, 256, 0, stream>>>(ynb, wob, outp, 4096, 2048, 4096);
}

// Round 3
// 1130.276 us; speedup vs baseline: 1.0278x; 1.0278x over previous
//
#include <hip/hip_runtime.h>
#include <cstdint>
#include <cstddef>

typedef __attribute__((ext_vector_type(8))) short short8;
typedef __attribute__((ext_vector_type(4))) short short4v;
typedef __attribute__((ext_vector_type(4))) float float4v;
typedef __attribute__((ext_vector_type(2))) float f32x2;
typedef __attribute__((ext_vector_type(4))) unsigned int uint4v;

#define DEV static __device__ __forceinline__

DEV float b2f(unsigned short u) { return __uint_as_float(((unsigned int)u) << 16); }
DEV unsigned short f2b(float f) {
  unsigned int u = __float_as_uint(f);
  u = (u + 0x7fffu + ((u >> 16) & 1u)) >> 16;
  return (unsigned short)u;
}

// ---- problem sizes ----
static constexpr int NP = 12416;   // padded fused-N: 8192 qkv + 4096 z + 32 a + 32 b + 64 pad

// ---- ws layout (bytes), lifetime-overlaid; peak ~162.5 MB ----
static constexpr size_t OFF_QKVZ = 0;                         // bf16 [4096][12416], live GEMM1->rms_silu
static constexpr size_t SZ_QKVZ  = (size_t)4096*12416*2;      // 101,711,872
static constexpr size_t OFF_XB   = SZ_QKVZ;                   // bf16 x [4096][2048], live cast->GEMM1
static constexpr size_t SZ_XB    = (size_t)4096*2048*2;       // 16,777,216
static constexpr size_t OFF_WCAT = OFF_XB + SZ_XB;            // bf16 [12416][2048], live prep->GEMM1
static constexpr size_t SZ_WCAT  = (size_t)NP*2048*2;         // 50,855,936  -> end 169,345,024
static constexpr size_t OFF_QKVS = OFF_XB;                    // bf16 [4096][8192], overlays xb+wcat (dead after GEMM1)
static constexpr size_t SZ_QKVS  = (size_t)4096*8192*2;       // 67,108,864  -> end 168,820,736 (fits)
static constexpr size_t OFF_YN   = OFF_XB;                    // bf16 [4096][4096], after scan (qkvs dead)
static constexpr size_t SZ_YN    = (size_t)4096*4096*2;       // 33,554,432
static constexpr size_t OFF_WOB  = OFF_YN + SZ_YN;            // bf16 Wout [2048][4096], after scan
static constexpr size_t SZ_WOB   = (size_t)2048*4096*2;       // -> end 152,043,520 (fits under 168.8M)
static constexpr size_t OFF_G    = OFF_WCAT + SZ_WCAT;        // f32 [4096][32]
static constexpr size_t OFF_BET  = OFF_G + (size_t)4096*32*4;
static constexpr size_t WS_NEED  = OFF_BET + (size_t)4096*32*4;  // 170,393,600 (~162.5 MiB)

// ---- helpers ----
DEV void gl16(const unsigned short* g, unsigned short* l) {
  __builtin_amdgcn_global_load_lds((const __attribute__((address_space(1))) unsigned int*)g,
                                   (__attribute__((address_space(3))) unsigned int*)l,
                                   16, 0, 0);
}

DEV void store_out(unsigned short* C, size_t off, float v) { C[off] = f2b(v); }
DEV void store_out(float* C, size_t off, float v)          { C[off] = v; }

// 8-lane (o-group) sum via DPP on the VALU pipe (no DS traffic).
// Stages: xor1 (quad_perm [1,0,3,2]=0xB1), xor2 (quad_perm [2,3,0,1]=0x4E),
// then row_half_mirror (0x141): after the first two stages values are equal
// within each quad, so the half-row mirror delivers the other quad's sum.
DEV float dpp_add8(float v) {
  int x = __builtin_amdgcn_update_dpp(0, __float_as_int(v), 0xB1, 0xf, 0xf, false);
  v += __int_as_float(x);
  x = __builtin_amdgcn_update_dpp(0, __float_as_int(v), 0x4E, 0xf, 0xf, false);
  v += __int_as_float(x);
  x = __builtin_amdgcn_update_dpp(0, __float_as_int(v), 0x141, 0xf, 0xf, false);
  v += __int_as_float(x);
  return v;
}

// unpack packed bf16 pair (one dword) -> f32x2
DEV f32x2 up2(unsigned int u) {
  f32x2 r;
  r[0] = __uint_as_float(u << 16);
  r[1] = __uint_as_float(u & 0xffff0000u);
  return r;
}

// ---- generic cast fp32 -> bf16 (n multiple of 4) ----
__global__ void castk(const float* __restrict__ in, unsigned short* __restrict__ out, int n4) {
  int idx = blockIdx.x * 256 + threadIdx.x;
  if (idx >= n4) return;
  float4v v = ((const float4v*)in)[idx];
  short4v o;
  o[0] = (short)f2b(v[0]); o[1] = (short)f2b(v[1]);
  o[2] = (short)f2b(v[2]); o[3] = (short)f2b(v[3]);
  ((short4v*)out)[idx] = o;
}

// ---- build concatenated weight [12416][2048] bf16 ----
__global__ void prep_wcat(const float* __restrict__ Wqkv, const float* __restrict__ Wz,
                          const float* __restrict__ Wa, const float* __restrict__ Wb,
                          unsigned short* __restrict__ Wcat) {
  size_t e4 = (size_t)blockIdx.x * 256 + threadIdx.x;
  if (e4 >= (size_t)NP * 2048 / 4) return;
  size_t e = e4 * 4;
  int row = (int)(e >> 11);
  int col = (int)(e & 2047);
  float4v v;
  if (row < 8192)       v = *(const float4v*)&Wqkv[(size_t)row * 2048 + col];
  else if (row < 12288) v = *(const float4v*)&Wz[(size_t)(row - 8192) * 2048 + col];
  else if (row < 12320) v = *(const float4v*)&Wa[(size_t)(row - 12288) * 2048 + col];
  else if (row < 12352) v = *(const float4v*)&Wb[(size_t)(row - 12320) * 2048 + col];
  else                  v = (float4v){0.f, 0.f, 0.f, 0.f};
  short4v o;
  o[0] = (short)f2b(v[0]); o[1] = (short)f2b(v[1]);
  o[2] = (short)f2b(v[2]); o[3] = (short)f2b(v[3]);
  *(short4v*)&Wcat[e] = o;
}

// ---- bf16 MFMA GEMM: C[M][N] = A[M][K] @ B[N][K]^T (m97 structure) ----
template <typename OutT>
__global__ __launch_bounds__(256)
void gemm_bt(const unsigned short* __restrict__ A, const unsigned short* __restrict__ B,
             OutT* __restrict__ C, int M, int N, int K) {
  __shared__ __align__(16) unsigned short lA[128 * 32];
  __shared__ __align__(16) unsigned short lB[128 * 32];
  const int t = threadIdx.x;
  const int bm = blockIdx.x, bn = blockIdx.y;
  const int wave = t >> 6, lane = t & 63;
  const int wm = (wave >> 1) * 64, wn = (wave & 1) * 64;
  const int l16 = lane & 15, lg = lane >> 4;

  const int srow = t >> 2, skof = (t & 3) * 8;
  const unsigned short* Ag = A + (size_t)(bm * 128 + srow) * K + skof;
  const unsigned short* Bg = B + (size_t)(bn * 128 + srow) * K + skof;
  unsigned short* lAp = &lA[srow * 32 + skof];
  unsigned short* lBp = &lB[srow * 32 + skof];

  float4v acc[4][4] = {};

  const int nk = K >> 5;
  for (int kt = 0; kt < nk; kt++) {
    const unsigned short* a0 = Ag + kt * 32;
    const unsigned short* b0 = Bg + kt * 32;
    gl16(a0, lAp);
    gl16(a0 + (size_t)64 * K, lAp + 64 * 32);
    gl16(b0, lBp);
    gl16(b0 + (size_t)64 * K, lBp + 64 * 32);
    __syncthreads();
    short8 av[4], bv[4];
#pragma unroll
    for (int i = 0; i < 4; i++) av[i] = *(const short8*)&lA[(wm + i * 16 + l16) * 32 + lg * 8];
#pragma unroll
    for (int j = 0; j < 4; j++) bv[j] = *(const short8*)&lB[(wn + j * 16 + l16) * 32 + lg * 8];
#pragma unroll
    for (int i = 0; i < 4; i++)
#pragma unroll
      for (int j = 0; j < 4; j++)
        acc[i][j] = __builtin_amdgcn_mfma_f32_16x16x32_bf16(av[i], bv[j], acc[i][j], 0, 0, 0);
    __syncthreads();
  }

#pragma unroll
  for (int i = 0; i < 4; i++) {
    int row0 = bm * 128 + wm + i * 16 + lg * 4;
#pragma unroll
    for (int j = 0; j < 4; j++) {
      int col = bn * 128 + wn + j * 16 + l16;
#pragma unroll
      for (int rr = 0; rr < 4; rr++) {
        store_out(C, (size_t)(row0 + rr) * N + col, acc[i][j][rr]);
      }
    }
  }
}

// ---- conv(KW=4) + silu + q/k L2-norm ----
__global__ __launch_bounds__(256)
void conv_silu_norm(const unsigned short* __restrict__ qkvz, const float* __restrict__ conv_w,
                    unsigned short* __restrict__ qkvs) {
  const int m = blockIdx.x;           // b*S + s
  const int sloc = m & 1023;
  const int t = threadIdx.x;
  const int c0 = t * 32;
  float out[32];
#pragma unroll
  for (int cc = 0; cc < 32; cc += 8) {
    const int c = c0 + cc;
    float a8[8] = {0.f, 0.f, 0.f, 0.f, 0.f, 0.f, 0.f, 0.f};
#pragma unroll
    for (int j = 0; j < 4; j++) {
      const int sj = sloc - 3 + j;
      if (sj >= 0) {
        short8 v8 = *(const short8*)&qkvz[(size_t)(m - 3 + j) * NP + c];
#pragma unroll
        for (int e = 0; e < 8; e++)
          a8[e] = fmaf(b2f((unsigned short)v8[e]), conv_w[(c + e) * 4 + j], a8[e]);
      }
    }
#pragma unroll
    for (int e = 0; e < 8; e++) { float x = a8[e]; out[cc + e] = x * (1.f / (1.f + expf(-x))); }
  }
  if (c0 < 4096) {  // q or k head: L2 normalize over 128 ch (4 threads/head)
    float ss = 0.f;
#pragma unroll
    for (int e = 0; e < 32; e++) ss += out[e] * out[e];
    ss += __shfl_xor(ss, 1);
    ss += __shfl_xor(ss, 2);
    float sc = rsqrtf(ss + 1e-6f);
    if (c0 < 2048) sc *= 0.08838834764831845f;  // * DK^-0.5 for q
#pragma unroll
    for (int e = 0; e < 32; e++) out[e] *= sc;
  }
  const size_t ob = (size_t)m * 8192 + c0;
#pragma unroll
  for (int cc = 0; cc < 32; cc += 8) {
    short8 w;
#pragma unroll
    for (int e = 0; e < 8; e++) w[e] = (short)f2b(out[cc + e]);
    *(short8*)&qkvs[ob + cc] = w;
  }
}

// ---- conv_state output: (B,CI,KW) fp32 from pre-conv qkv ----
__global__ void conv_state_k(const unsigned short* __restrict__ qkvz, float* __restrict__ cs) {
  int idx = blockIdx.x * 256 + threadIdx.x;  // < 131072 = 4*8192*4
  int b = idx >> 15;
  int rem = idx & 32767;
  int c = rem >> 2;
  int j = rem & 3;
  cs[idx] = b2f(qkvz[(size_t)(b * 1024 + 1020 + j) * NP + c]);
}

// ---- g / beta from a,b columns ----
__global__ void gb_kernel(const unsigned short* __restrict__ qkvz, const float* __restrict__ A_log,
                          const float* __restrict__ dt_bias, float* __restrict__ g,
                          float* __restrict__ bet) {
  int idx = blockIdx.x * 256 + threadIdx.x;  // < 4096*64
  int m = idx >> 6, n = idx & 63;
  if (n < 32) {
    float a = b2f(qkvz[(size_t)m * NP + 12288 + n]) + dt_bias[n];
    float sp = (a > 20.f) ? a : log1pf(expf(a));
    g[m * 32 + n] = -expf(A_log[n]) * sp;
  } else {
    int nn = n - 32;
    float bb = b2f(qkvz[(size_t)m * NP + 12320 + nn]);
    bet[m * 32 + nn] = 1.f / (1.f + expf(-bb));
  }
}

// ---- sequential delta-rule scan, rows (DV) independent ----
// grid 256 = (b, h, dv-half); 512 threads: 8 threads per v-row x 16 state floats.
// v2: bf16 LDS (half DS bytes), DPP reductions (off the DS pipe), readlane g/beta.
__global__ __launch_bounds__(512)
void scan_kernel(const unsigned short* __restrict__ qkvs, const float* __restrict__ g,
                 const float* __restrict__ bet, unsigned short* __restrict__ y,
                 float* __restrict__ state_out) {
  __shared__ __align__(16) unsigned short kch[32][128];
  __shared__ __align__(16) unsigned short qch[32][128];
  __shared__ __align__(16) unsigned short vch[32][64];
  __shared__ float gch[32];
  __shared__ float bch[32];
  __shared__ float obuf[32][64];
  const int bid = blockIdx.x;
  const int b = bid >> 6;
  const int h = (bid >> 1) & 31;
  const int half = bid & 1;
  const int hk = h >> 1;
  const int t = threadIdx.x;
  const int r = t >> 3, o = t & 7;
  f32x2 s2[8];
#pragma unroll
  for (int j = 0; j < 8; j++) s2[j] = (f32x2){0.f, 0.f};

  const int stg_step = t >> 4, stg16 = t & 15;

  for (int ch = 0; ch < 32; ch++) {
    const int s0 = ch << 5;
    {
      size_t row = (size_t)((b << 10) + s0 + stg_step) * 8192;
      *(short8*)&kch[stg_step][stg16 * 8] = *(const short8*)&qkvs[row + 2048 + hk * 128 + stg16 * 8];
      *(short8*)&qch[stg_step][stg16 * 8] = *(const short8*)&qkvs[row + hk * 128 + stg16 * 8];
      if (stg16 < 8)
        *(short8*)&vch[stg_step][stg16 * 8] =
            *(const short8*)&qkvs[row + 4096 + h * 128 + half * 64 + stg16 * 8];
      if (t < 32) gch[t] = expf(g[((b << 10) + s0 + t) * 32 + h]);
      else if (t < 64) bch[t - 32] = bet[((b << 10) + s0 + (t - 32)) * 32 + h];
    }
    __syncthreads();
    const int greg = __float_as_int(gch[t & 31]);
    const int breg = __float_as_int(bch[t & 31]);
#pragma unroll 1
    for (int i = 0; i < 32; i++) {
      const float gam = __int_as_float(__builtin_amdgcn_readlane(greg, i));
      const float be  = __int_as_float(__builtin_amdgcn_readlane(breg, i));
      const float vr  = b2f(vch[i][r]);
      const uint4v k0 = *(const uint4v*)&kch[i][o * 16];
      const uint4v k1 = *(const uint4v*)&kch[i][o * 16 + 8];
      const uint4v q0 = *(const uint4v*)&qch[i][o * 16];
      const uint4v q1 = *(const uint4v*)&qch[i][o * 16 + 8];
      f32x2 kk2[8], qq2[8];
#pragma unroll
      for (int w = 0; w < 4; w++) {
        kk2[w] = up2(k0[w]); kk2[4 + w] = up2(k1[w]);
        qq2[w] = up2(q0[w]); qq2[4 + w] = up2(q1[w]);
      }
      f32x2 pa = s2[0] * kk2[0], pb = s2[1] * kk2[1];
      f32x2 pc = s2[2] * kk2[2], pd = s2[3] * kk2[3];
      pa += s2[4] * kk2[4]; pb += s2[5] * kk2[5];
      pc += s2[6] * kk2[6]; pd += s2[7] * kk2[7];
      pa += pb; pc += pd; pa += pc;
      float p = dpp_add8(pa[0] + pa[1]);
      const float dl = be * (vr - gam * p);
      const f32x2 g2v = {gam, gam};
      const f32x2 dl2 = {dl, dl};
      f32x2 oa, ob, oc, od;
      s2[0] = g2v * s2[0] + dl2 * kk2[0]; oa = s2[0] * qq2[0];
      s2[1] = g2v * s2[1] + dl2 * kk2[1]; ob = s2[1] * qq2[1];
      s2[2] = g2v * s2[2] + dl2 * kk2[2]; oc = s2[2] * qq2[2];
      s2[3] = g2v * s2[3] + dl2 * kk2[3]; od = s2[3] * qq2[3];
      s2[4] = g2v * s2[4] + dl2 * kk2[4]; oa += s2[4] * qq2[4];
      s2[5] = g2v * s2[5] + dl2 * kk2[5]; ob += s2[5] * qq2[5];
      s2[6] = g2v * s2[6] + dl2 * kk2[6]; oc += s2[6] * qq2[6];
      s2[7] = g2v * s2[7] + dl2 * kk2[7]; od += s2[7] * qq2[7];
      oa += ob; oc += od; oa += oc;
      float op = dpp_add8(oa[0] + oa[1]);
      if (o == 0) obuf[i][r] = op;
    }
    __syncthreads();
#pragma unroll
    for (int idx = t; idx < 2048; idx += 512) {
      int st = idx >> 6, vv = idx & 63;
      y[(size_t)((b << 10) + s0 + st) * 4096 + h * 128 + half * 64 + vv] = f2b(obuf[st][vv]);
    }
    __syncthreads();
  }
  float* sp = state_out + ((size_t)((b * 32 + h) * 128 + half * 64 + r)) * 128 + o * 16;
#pragma unroll
  for (int j = 0; j < 8; j++) *(f32x2*)&sp[2 * j] = s2[j];
}

// ---- RMSNorm over DV * norm_w * silu(z) -> yn bf16 ----
__global__ __launch_bounds__(256)
void rms_silu(const unsigned short* __restrict__ y, const unsigned short* __restrict__ qkvz,
              const float* __restrict__ nw, unsigned short* __restrict__ yn) {
  int m = blockIdx.x;
  int t = threadIdx.x;
  int head = t >> 3, oct = t & 7;
  int vb = head * 128 + oct * 16;
  const unsigned short* yp = y + (size_t)m * 4096 + vb;
  float yy[16];
  short8 y0 = *(const short8*)yp, y1 = *(const short8*)(yp + 8);
#pragma unroll
  for (int e = 0; e < 8; e++) { yy[e] = b2f((unsigned short)y0[e]); yy[8 + e] = b2f((unsigned short)y1[e]); }
  float ss = 0.f;
#pragma unroll
  for (int e = 0; e < 16; e++) ss += yy[e] * yy[e];
  ss += __shfl_xor(ss, 1); ss += __shfl_xor(ss, 2); ss += __shfl_xor(ss, 4);
  float rinv = rsqrtf(ss * (1.f / 128.f) + 1e-6f);
  const unsigned short* zp = qkvz + (size_t)m * NP + 8192 + vb;
  short8 z0 = *(const short8*)zp, z1 = *(const short8*)(zp + 8);
  short8 o0, o1;
#pragma unroll
  for (int e = 0; e < 8; e++) {
    float z = b2f((unsigned short)z0[e]);
    float v = nw[oct * 16 + e] * yy[e] * rinv * (z / (1.f + expf(-z)));
    o0[e] = (short)f2b(v);
    z = b2f((unsigned short)z1[e]);
    v = nw[oct * 16 + 8 + e] * yy[8 + e] * rinv * (z / (1.f + expf(-z)));
    o1[e] = (short)f2b(v);
  }
  unsigned short* op = yn + (size_t)m * 4096 + vb;
  *(short8*)op = o0;
  *(short8*)(op + 8) = o1;
}

extern "C" void kernel_launch(void* const* d_in, const int* in_sizes, int n_in,
                              void* d_out, int out_size, void* d_ws, size_t ws_size,
                              hipStream_t stream) {
  if (ws_size < WS_NEED) return;  // guard: fail with clean absmax, not a fault

  const float* x     = (const float*)d_in[0];
  const float* Wqkv  = (const float*)d_in[1];
  const float* Wz    = (const float*)d_in[2];
  const float* Wa    = (const float*)d_in[3];
  const float* Wb    = (const float*)d_in[4];
  const float* convw = (const float*)d_in[5];
  const float* Alog  = (const float*)d_in[6];
  const float* dtb   = (const float*)d_in[7];
  const float* nw    = (const float*)d_in[8];
  const float* Wout  = (const float*)d_in[9];

  char* ws = (char*)d_ws;
  unsigned short* qkvz = (unsigned short*)(ws + OFF_QKVZ);
  unsigned short* xb   = (unsigned short*)(ws + OFF_XB);
  unsigned short* wcat = (unsigned short*)(ws + OFF_WCAT);
  unsigned short* qkvs = (unsigned short*)(ws + OFF_QKVS);
  unsigned short* ynb  = (unsigned short*)(ws + OFF_YN);
  unsigned short* wob  = (unsigned short*)(ws + OFF_WOB);
  float* gbuf          = (float*)(ws + OFF_G);
  float* bbuf          = (float*)(ws + OFF_BET);

  float* outp       = (float*)d_out;
  float* conv_state = outp + 8388608;             // B*S*H
  float* state      = outp + 8388608 + 131072;    // + B*CI*KW
  unsigned short* ybuf = (unsigned short*)d_out;  // y bf16 scratch over outp region (rewritten by gemm2)

  castk<<<8192, 256, 0, stream>>>(x, xb, 2097152);
  prep_wcat<<<24832, 256, 0, stream>>>(Wqkv, Wz, Wa, Wb, wcat);

  dim3 g1(32, 97);
  gemm_bt<unsigned short><<<g1, 256, 0, stream>>>(xb, wcat, qkvz, 4096, NP, 2048);

  conv_silu_norm<<<4096, 256, 0, stream>>>(qkvz, convw, qkvs);
  conv_state_k<<<512, 256, 0, stream>>>(qkvz, conv_state);
  gb_kernel<<<1024, 256, 0, stream>>>(qkvz, Alog, dtb, gbuf, bbuf);

  scan_kernel<<<256, 512, 0, stream>>>(qkvs, gbuf, bbuf, ybuf, state);

  rms_silu<<<4096, 256, 0, stream>>>(ybuf, qkvz, nw, ynb);
  castk<<<8192, 256, 0, stream>>>(Wout, wob, 2097152);

  dim3 g2(32, 16);
  gemm_bt<float><<<g2, 256, 0, stream>>>(ynb, wob, outp, 4096, 2048, 4096);
}

// Round 4
// 869.567 us; speedup vs baseline: 1.3359x; 1.2998x over previous
//
#include <hip/hip_runtime.h>
#include <cstdint>
#include <cstddef>

typedef __attribute__((ext_vector_type(8))) short short8;
typedef __attribute__((ext_vector_type(4))) short short4v;
typedef __attribute__((ext_vector_type(4))) float float4v;

#define DEV static __device__ __forceinline__

DEV float b2f(unsigned short u) { return __uint_as_float(((unsigned int)u) << 16); }
DEV unsigned short f2b(float f) {
  unsigned int u = __float_as_uint(f);
  u = (u + 0x7fffu + ((u >> 16) & 1u)) >> 16;
  return (unsigned short)u;
}

#define MFMA32(a, b, c) __builtin_amdgcn_mfma_f32_16x16x32_bf16(a, b, c, 0, 0, 0)

// ---- problem sizes ----
static constexpr int NP = 12416;   // padded fused-N: 8192 qkv + 4096 z + 32 a + 32 b + 64 pad

// ---- ws layout (bytes), lifetime-overlaid; peak ~162.5 MB ----
static constexpr size_t OFF_QKVZ = 0;
static constexpr size_t SZ_QKVZ  = (size_t)4096*12416*2;
static constexpr size_t OFF_XB   = SZ_QKVZ;
static constexpr size_t SZ_XB    = (size_t)4096*2048*2;
static constexpr size_t OFF_WCAT = OFF_XB + SZ_XB;
static constexpr size_t SZ_WCAT  = (size_t)NP*2048*2;
static constexpr size_t OFF_QKVS = OFF_XB;          // overlays xb+wcat after GEMM1
static constexpr size_t SZ_QKVS  = (size_t)4096*8192*2;
static constexpr size_t OFF_YN   = OFF_XB;          // after scan
static constexpr size_t SZ_YN    = (size_t)4096*4096*2;
static constexpr size_t OFF_WOB  = OFF_YN + SZ_YN;
static constexpr size_t SZ_WOB   = (size_t)2048*4096*2;
static constexpr size_t OFF_G    = OFF_WCAT + SZ_WCAT;
static constexpr size_t OFF_BET  = OFF_G + (size_t)4096*32*4;
static constexpr size_t WS_NEED  = OFF_BET + (size_t)4096*32*4;

// ---- helpers ----
DEV void gl16(const unsigned short* g, unsigned short* l) {
  __builtin_amdgcn_global_load_lds((const __attribute__((address_space(1))) unsigned int*)g,
                                   (__attribute__((address_space(3))) unsigned int*)l,
                                   16, 0, 0);
}

DEV void store_out(unsigned short* C, size_t off, float v) { C[off] = f2b(v); }
DEV void store_out(float* C, size_t off, float v)          { C[off] = v; }

// ---- generic cast fp32 -> bf16 (n multiple of 4) ----
__global__ void castk(const float* __restrict__ in, unsigned short* __restrict__ out, int n4) {
  int idx = blockIdx.x * 256 + threadIdx.x;
  if (idx >= n4) return;
  float4v v = ((const float4v*)in)[idx];
  short4v o;
  o[0] = (short)f2b(v[0]); o[1] = (short)f2b(v[1]);
  o[2] = (short)f2b(v[2]); o[3] = (short)f2b(v[3]);
  ((short4v*)out)[idx] = o;
}

// ---- build concatenated weight [12416][2048] bf16 ----
__global__ void prep_wcat(const float* __restrict__ Wqkv, const float* __restrict__ Wz,
                          const float* __restrict__ Wa, const float* __restrict__ Wb,
                          unsigned short* __restrict__ Wcat) {
  size_t e4 = (size_t)blockIdx.x * 256 + threadIdx.x;
  if (e4 >= (size_t)NP * 2048 / 4) return;
  size_t e = e4 * 4;
  int row = (int)(e >> 11);
  int col = (int)(e & 2047);
  float4v v;
  if (row < 8192)       v = *(const float4v*)&Wqkv[(size_t)row * 2048 + col];
  else if (row < 12288) v = *(const float4v*)&Wz[(size_t)(row - 8192) * 2048 + col];
  else if (row < 12320) v = *(const float4v*)&Wa[(size_t)(row - 12288) * 2048 + col];
  else if (row < 12352) v = *(const float4v*)&Wb[(size_t)(row - 12320) * 2048 + col];
  else                  v = (float4v){0.f, 0.f, 0.f, 0.f};
  short4v o;
  o[0] = (short)f2b(v[0]); o[1] = (short)f2b(v[1]);
  o[2] = (short)f2b(v[2]); o[3] = (short)f2b(v[3]);
  *(short4v*)&Wcat[e] = o;
}

// ---- bf16 MFMA GEMM: C[M][N] = A[M][K] @ B[N][K]^T (m97 structure) ----
template <typename OutT>
__global__ __launch_bounds__(256)
void gemm_bt(const unsigned short* __restrict__ A, const unsigned short* __restrict__ B,
             OutT* __restrict__ C, int M, int N, int K) {
  __shared__ __align__(16) unsigned short lA[128 * 32];
  __shared__ __align__(16) unsigned short lB[128 * 32];
  const int t = threadIdx.x;
  const int bm = blockIdx.x, bn = blockIdx.y;
  const int wave = t >> 6, lane = t & 63;
  const int wm = (wave >> 1) * 64, wn = (wave & 1) * 64;
  const int l16 = lane & 15, lg = lane >> 4;

  const int srow = t >> 2, skof = (t & 3) * 8;
  const unsigned short* Ag = A + (size_t)(bm * 128 + srow) * K + skof;
  const unsigned short* Bg = B + (size_t)(bn * 128 + srow) * K + skof;
  unsigned short* lAp = &lA[srow * 32 + skof];
  unsigned short* lBp = &lB[srow * 32 + skof];

  float4v acc[4][4] = {};

  const int nk = K >> 5;
  for (int kt = 0; kt < nk; kt++) {
    const unsigned short* a0 = Ag + kt * 32;
    const unsigned short* b0 = Bg + kt * 32;
    gl16(a0, lAp);
    gl16(a0 + (size_t)64 * K, lAp + 64 * 32);
    gl16(b0, lBp);
    gl16(b0 + (size_t)64 * K, lBp + 64 * 32);
    __syncthreads();
    short8 av[4], bv[4];
#pragma unroll
    for (int i = 0; i < 4; i++) av[i] = *(const short8*)&lA[(wm + i * 16 + l16) * 32 + lg * 8];
#pragma unroll
    for (int j = 0; j < 4; j++) bv[j] = *(const short8*)&lB[(wn + j * 16 + l16) * 32 + lg * 8];
#pragma unroll
    for (int i = 0; i < 4; i++)
#pragma unroll
      for (int j = 0; j < 4; j++)
        acc[i][j] = MFMA32(av[i], bv[j], acc[i][j]);
    __syncthreads();
  }

#pragma unroll
  for (int i = 0; i < 4; i++) {
    int row0 = bm * 128 + wm + i * 16 + lg * 4;
#pragma unroll
    for (int j = 0; j < 4; j++) {
      int col = bn * 128 + wn + j * 16 + l16;
#pragma unroll
      for (int rr = 0; rr < 4; rr++) {
        store_out(C, (size_t)(row0 + rr) * N + col, acc[i][j][rr]);
      }
    }
  }
}

// ---- conv(KW=4) + silu + q/k L2-norm ----
__global__ __launch_bounds__(256)
void conv_silu_norm(const unsigned short* __restrict__ qkvz, const float* __restrict__ conv_w,
                    unsigned short* __restrict__ qkvs) {
  const int m = blockIdx.x;           // b*S + s
  const int sloc = m & 1023;
  const int t = threadIdx.x;
  const int c0 = t * 32;
  float out[32];
#pragma unroll
  for (int cc = 0; cc < 32; cc += 8) {
    const int c = c0 + cc;
    float a8[8] = {0.f, 0.f, 0.f, 0.f, 0.f, 0.f, 0.f, 0.f};
#pragma unroll
    for (int j = 0; j < 4; j++) {
      const int sj = sloc - 3 + j;
      if (sj >= 0) {
        short8 v8 = *(const short8*)&qkvz[(size_t)(m - 3 + j) * NP + c];
#pragma unroll
        for (int e = 0; e < 8; e++)
          a8[e] = fmaf(b2f((unsigned short)v8[e]), conv_w[(c + e) * 4 + j], a8[e]);
      }
    }
#pragma unroll
    for (int e = 0; e < 8; e++) { float x = a8[e]; out[cc + e] = x * (1.f / (1.f + expf(-x))); }
  }
  if (c0 < 4096) {  // q or k head: L2 normalize over 128 ch (4 threads/head)
    float ss = 0.f;
#pragma unroll
    for (int e = 0; e < 32; e++) ss += out[e] * out[e];
    ss += __shfl_xor(ss, 1);
    ss += __shfl_xor(ss, 2);
    float sc = rsqrtf(ss + 1e-6f);
    if (c0 < 2048) sc *= 0.08838834764831845f;  // * DK^-0.5 for q
#pragma unroll
    for (int e = 0; e < 32; e++) out[e] *= sc;
  }
  const size_t ob = (size_t)m * 8192 + c0;
#pragma unroll
  for (int cc = 0; cc < 32; cc += 8) {
    short8 w;
#pragma unroll
    for (int e = 0; e < 8; e++) w[e] = (short)f2b(out[cc + e]);
    *(short8*)&qkvs[ob + cc] = w;
  }
}

// ---- conv_state output: (B,CI,KW) fp32 from pre-conv qkv ----
__global__ void conv_state_k(const unsigned short* __restrict__ qkvz, float* __restrict__ cs) {
  int idx = blockIdx.x * 256 + threadIdx.x;  // < 131072 = 4*8192*4
  int b = idx >> 15;
  int rem = idx & 32767;
  int c = rem >> 2;
  int j = rem & 3;
  cs[idx] = b2f(qkvz[(size_t)(b * 1024 + 1020 + j) * NP + c]);
}

// ---- g / beta from a,b columns ----
__global__ void gb_kernel(const unsigned short* __restrict__ qkvz, const float* __restrict__ A_log,
                          const float* __restrict__ dt_bias, float* __restrict__ g,
                          float* __restrict__ bet) {
  int idx = blockIdx.x * 256 + threadIdx.x;  // < 4096*64
  int m = idx >> 6, n = idx & 63;
  if (n < 32) {
    float a = b2f(qkvz[(size_t)m * NP + 12288 + n]) + dt_bias[n];
    float sp = (a > 20.f) ? a : log1pf(expf(a));
    g[m * 32 + n] = -expf(A_log[n]) * sp;
  } else {
    int nn = n - 32;
    float bb = b2f(qkvz[(size_t)m * NP + 12320 + nn]);
    bet[m * 32 + nn] = 1.f / (1.f + expf(-bb));
  }
}

// ---- chunked delta-rule scan (UT transform), C=64, MFMA throughout ----
// grid 256 = (b, h, dv-half); 256 threads = 4 waves.
// State S[v][d] (v-half 64 x DK 128) in fp32 accumulators, bf16 mirror in LDS.
__global__ __launch_bounds__(256)
void scan_chunk(const unsigned short* __restrict__ qkvs, const float* __restrict__ g,
                const float* __restrict__ bet, unsigned short* __restrict__ y,
                float* __restrict__ state_out) {
  __shared__ __align__(16) unsigned short Kb[64][128];
  __shared__ __align__(16) unsigned short Qb[64][128];
  __shared__ __align__(16) unsigned short Sb[64][128];
  __shared__ __align__(16) unsigned short Ktt[128][64];
  __shared__ __align__(16) unsigned short Mb[64][64];
  __shared__ __align__(16) unsigned short Nb[64][64];
  __shared__ __align__(16) unsigned short Dbf[64][64];
  __shared__ __align__(16) unsigned short Vt[64][64];   // also reused as obuf
  __shared__ __align__(16) unsigned short Tb[4][16][16];
  __shared__ __align__(16) unsigned short rtmp[64][16];
  __shared__ float Gar[64];
  __shared__ float gamv[64];
  __shared__ float barr[64];
  __shared__ float gcs[2];

  const int bid = blockIdx.x;
  const int b = bid >> 6;
  const int h = (bid >> 1) & 31;
  const int half = bid & 1;
  const int hk = h >> 1;
  const int t = threadIdx.x;
  const int wv = t >> 6, lane = t & 63;
  const int l16 = lane & 15, lg = lane >> 4;
  const int bS = b << 10;

  float4v accS[8] = {};
  for (int idx = t; idx < 64 * 128; idx += 256) (&Sb[0][0])[idx] = 0;

  for (int ch = 0; ch < 16; ch++) {
    const int s0 = ch << 6;
    // ---- phase 1: stage Kb, Qb (swizzled via source permutation), Vt, g/beta ----
    {
#pragma unroll
      for (int rep = 0; rep < 4; rep++) {
        int rb = wv * 16 + rep * 4;
        int i = rb + (lane >> 4);
        int cg = (lane & 15) ^ (i & 7);
        const unsigned short* gk = qkvs + (size_t)(bS + s0 + i) * 8192 + 2048 + hk * 128 + cg * 8;
        gl16(gk, &Kb[rb][0] + lane * 8);
        const unsigned short* gq = qkvs + (size_t)(bS + s0 + i) * 8192 + hk * 128 + cg * 8;
        gl16(gq, &Qb[rb][0] + lane * 8);
      }
    }
    {
      int tt = t >> 2, q4 = t & 3;
      const unsigned short* gv = qkvs + (size_t)(bS + s0 + tt) * 8192 + 4096 + h * 128 + half * 64 + q4 * 16;
      short8 v0 = *(const short8*)gv;
      short8 v1 = *(const short8*)(gv + 8);
#pragma unroll
      for (int e = 0; e < 8; e++) {
        int v = q4 * 16 + e;
        Vt[v][tt ^ ((v & 7) << 3)] = (unsigned short)v0[e];
        v = q4 * 16 + 8 + e;
        Vt[v][tt ^ ((v & 7) << 3)] = (unsigned short)v1[e];
      }
    }
    if (t < 64) {
      float gt = g[(bS + s0 + t) * 32 + h];
      float bt = bet[(bS + s0 + t) * 32 + h];
#pragma unroll
      for (int d = 1; d < 64; d <<= 1) {
        float o = __shfl_up(gt, d);
        if (t >= d) gt += o;
      }
      Gar[t] = gt;
      gamv[t] = __expf(gt);
      barr[t] = bt;
      if (t == 63) { gcs[0] = gt; gcs[1] = __expf(gt); }
    }
    __syncthreads();

    // ---- phase 2: KK^T -> Mb, QK^T -> Nb; build Ktt ----
    {
      float4v aK[4] = {}, aQ[4] = {};
      const int arow = wv * 16 + l16;
      const int asw = (arow & 7) << 3;
#pragma unroll
      for (int kk = 0; kk < 4; kk++) {
        short8 av = *(const short8*)&Kb[arow][(kk * 32 + lg * 8) ^ asw];
        short8 aq = *(const short8*)&Qb[arow][(kk * 32 + lg * 8) ^ asw];
#pragma unroll
        for (int j = 0; j < 4; j++) {
          int brow = j * 16 + l16;
          short8 bv = *(const short8*)&Kb[brow][(kk * 32 + lg * 8) ^ ((brow & 7) << 3)];
          aK[j] = MFMA32(av, bv, aK[j]);
          aQ[j] = MFMA32(aq, bv, aQ[j]);
        }
      }
#pragma unroll
      for (int j = 0; j < 4; j++) {
#pragma unroll
        for (int reg = 0; reg < 4; reg++) {
          int tt = wv * 16 + lg * 4 + reg;
          int ii = j * 16 + l16;
          float sc = __expf(Gar[tt] - Gar[ii]);
          float mv = (ii < tt) ? aK[j][reg] * barr[tt] * sc : 0.f;
          float nv = (ii <= tt) ? aQ[j][reg] * sc : 0.f;
          Mb[tt][(ii ^ ((tt & 7) << 3))] = f2b(mv);
          Nb[tt][(ii ^ ((tt & 7) << 3))] = f2b(nv);
        }
      }
    }
    {
      int i = t >> 2, q4 = t & 3;
      float sc = __expf(gcs[0] - Gar[i]);
      int isw = (i & 7) << 3;
#pragma unroll
      for (int e8 = 0; e8 < 4; e8++) {
        int d0 = q4 * 32 + e8 * 8;
        short8 kv = *(const short8*)&Kb[i][d0 ^ isw];
#pragma unroll
        for (int e = 0; e < 8; e++) {
          int d = d0 + e;
          Ktt[d][i ^ ((d & 7) << 3)] = f2b(b2f((unsigned short)kv[e]) * sc);
        }
      }
    }
    __syncthreads();

    // ---- phase 3: P0t = S0 K^T; RHS -> Dbf; T-inverse -> Tb ----
    {
      float4v acc[4] = {};
      const int arow = wv * 16 + l16;  // v
      const int asw = (arow & 7) << 3;
#pragma unroll
      for (int kk = 0; kk < 4; kk++) {
        short8 av = *(const short8*)&Sb[arow][(kk * 32 + lg * 8) ^ asw];
#pragma unroll
        for (int j = 0; j < 4; j++) {
          int brow = j * 16 + l16;  // t
          short8 bv = *(const short8*)&Kb[brow][(kk * 32 + lg * 8) ^ ((brow & 7) << 3)];
          acc[j] = MFMA32(av, bv, acc[j]);
        }
      }
#pragma unroll
      for (int j = 0; j < 4; j++) {
#pragma unroll
        for (int reg = 0; reg < 4; reg++) {
          int v = wv * 16 + lg * 4 + reg;
          int tt = j * 16 + l16;
          float vtv = b2f(Vt[v][tt ^ ((v & 7) << 3)]);
          float val = barr[tt] * (vtv - gamv[tt] * acc[j][reg]);
          Dbf[v][tt ^ ((v & 7) << 3)] = f2b(val);
        }
      }
    }
    {
      // T-inverse of diagonal block wv (unit lower): lane l16 = column j, holds row l16 of L
      float Lrow[16];
#pragma unroll
      for (int i = 0; i < 16; i++)
        Lrow[i] = b2f(Mb[wv * 16 + l16][((wv * 16 + i) ^ ((l16 & 7) << 3))]);
      float Tc[16];
#pragma unroll
      for (int i = 0; i < 16; i++) Tc[i] = (i == l16) ? 1.f : 0.f;
#pragma unroll
      for (int tt = 1; tt < 16; tt++) {
        float s = 0.f;
#pragma unroll
        for (int i = 0; i < 16; i++) {
          if (i < tt)
            s += __int_as_float(__builtin_amdgcn_readlane(__float_as_int(Lrow[i]), tt)) * Tc[i];
        }
        Tc[tt] = ((tt == l16) ? 1.f : 0.f) - s;
      }
      if (lane < 16) {
#pragma unroll
        for (int tt = 0; tt < 16; tt++) Tb[wv][tt][l16] = f2b(Tc[tt]);
      }
    }
    __syncthreads();

    // ---- phase 4: block forward substitution, D = (I+M)^{-1} RHS ----
    {
      // stage 0: Dt_0 = Rt_0 @ T_0^T (in place)
      short8 a = (short8)(short)0, bT = (short8)(short)0;
      const int arow = wv * 16 + l16;
      if (lg < 2) {
        a = *(const short8*)&Dbf[arow][((lg * 8) ^ ((arow & 7) << 3))];
        bT = *(const short8*)&Tb[0][l16][lg * 8];
      }
      float4v acc0 = {};
      acc0 = MFMA32(a, bT, acc0);
      __syncthreads();
#pragma unroll
      for (int reg = 0; reg < 4; reg++) {
        int v = wv * 16 + lg * 4 + reg;
        Dbf[v][(l16 ^ ((v & 7) << 3))] = f2b(acc0[reg]);
      }
    }
    __syncthreads();
#pragma unroll
    for (int s = 1; s < 4; s++) {
      float4v acc = {};
      const int arow = wv * 16 + l16;
      const int mrow = s * 16 + l16;
#pragma unroll
      for (int j = 0; j < 3; j++) {
        if (j < s) {
          short8 a = (short8)(short)0, bM = (short8)(short)0;
          if (lg < 2) {
            a  = *(const short8*)&Dbf[arow][((j * 16 + lg * 8) ^ ((arow & 7) << 3))];
            bM = *(const short8*)&Mb[mrow][((j * 16 + lg * 8) ^ ((mrow & 7) << 3))];
          }
          acc = MFMA32(a, bM, acc);
        }
      }
#pragma unroll
      for (int reg = 0; reg < 4; reg++) {
        int v = wv * 16 + lg * 4 + reg;
        float rt = b2f(Dbf[v][((s * 16 + l16) ^ ((v & 7) << 3))]);
        rtmp[v][l16] = f2b(rt - acc[reg]);
      }
      __syncthreads();
      short8 a2 = (short8)(short)0, bT = (short8)(short)0;
      if (lg < 2) {
        a2 = *(const short8*)&rtmp[wv * 16 + l16][lg * 8];
        bT = *(const short8*)&Tb[s][l16][lg * 8];
      }
      float4v acc2 = {};
      acc2 = MFMA32(a2, bT, acc2);
      __syncthreads();
#pragma unroll
      for (int reg = 0; reg < 4; reg++) {
        int v = wv * 16 + lg * 4 + reg;
        Dbf[v][((s * 16 + l16) ^ ((v & 7) << 3))] = f2b(acc2[reg]);
      }
      __syncthreads();
    }

    // ---- phase 5: O = diag(gam) Q S0^T + N D ----
    {
      float4v acc[4] = {};
      const int arow = wv * 16 + l16;  // t
      const int asw = (arow & 7) << 3;
#pragma unroll
      for (int kk = 0; kk < 4; kk++) {
        short8 aq = *(const short8*)&Qb[arow][(kk * 32 + lg * 8) ^ asw];
#pragma unroll
        for (int j = 0; j < 4; j++) {
          int brow = j * 16 + l16;  // v
          short8 bs = *(const short8*)&Sb[brow][(kk * 32 + lg * 8) ^ ((brow & 7) << 3)];
          acc[j] = MFMA32(aq, bs, acc[j]);
        }
      }
#pragma unroll
      for (int j = 0; j < 4; j++) {
#pragma unroll
        for (int reg = 0; reg < 4; reg++) {
          int tt = wv * 16 + lg * 4 + reg;
          acc[j][reg] *= gamv[tt];
        }
      }
#pragma unroll
      for (int kk = 0; kk < 2; kk++) {
        short8 an = *(const short8*)&Nb[arow][(kk * 32 + lg * 8) ^ asw];
#pragma unroll
        for (int j = 0; j < 4; j++) {
          int brow = j * 16 + l16;  // v
          short8 bd = *(const short8*)&Dbf[brow][(kk * 32 + lg * 8) ^ ((brow & 7) << 3)];
          acc[j] = MFMA32(an, bd, acc[j]);
        }
      }
      __syncthreads();  // Vt (V data) fully consumed; reuse as obuf
#pragma unroll
      for (int j = 0; j < 4; j++) {
#pragma unroll
        for (int reg = 0; reg < 4; reg++) {
          int tt = wv * 16 + lg * 4 + reg;
          int v = j * 16 + l16;
          Vt[tt][v ^ ((tt & 7) << 3)] = f2b(acc[j][reg]);
        }
      }
    }
    __syncthreads();
    {
      int tt = t >> 2, q4 = t & 3;
      int sw = (tt & 7) << 3;
      unsigned short* yg = y + (size_t)(bS + s0 + tt) * 4096 + h * 128 + half * 64 + q4 * 16;
      short8 o0 = *(const short8*)&Vt[tt][(q4 * 16) ^ sw];
      short8 o1 = *(const short8*)&Vt[tt][(q4 * 16 + 8) ^ sw];
      *(short8*)yg = o0;
      *(short8*)(yg + 8) = o1;
    }

    // ---- phase 6: state update S = gamC * S + D^T Ktt ----
    {
      float gC = gcs[1];
#pragma unroll
      for (int dt = 0; dt < 8; dt++)
#pragma unroll
        for (int reg = 0; reg < 4; reg++) accS[dt][reg] *= gC;
      const int arow = wv * 16 + l16;  // v
      const int asw = (arow & 7) << 3;
#pragma unroll
      for (int kk = 0; kk < 2; kk++) {
        short8 ad = *(const short8*)&Dbf[arow][(kk * 32 + lg * 8) ^ asw];
#pragma unroll
        for (int dt = 0; dt < 8; dt++) {
          int brow = dt * 16 + l16;  // d
          short8 bk = *(const short8*)&Ktt[brow][(kk * 32 + lg * 8) ^ ((brow & 7) << 3)];
          accS[dt] = MFMA32(ad, bk, accS[dt]);
        }
      }
      __syncthreads();
#pragma unroll
      for (int dt = 0; dt < 8; dt++) {
#pragma unroll
        for (int reg = 0; reg < 4; reg++) {
          int v = wv * 16 + lg * 4 + reg;
          int d = dt * 16 + l16;
          Sb[v][d ^ ((v & 7) << 3)] = f2b(accS[dt][reg]);
        }
      }
    }
    __syncthreads();
  }

  // final state writeout (fp32)
#pragma unroll
  for (int dt = 0; dt < 8; dt++) {
#pragma unroll
    for (int reg = 0; reg < 4; reg++) {
      int v = wv * 16 + lg * 4 + reg;
      int d = dt * 16 + l16;
      state_out[((size_t)((b * 32 + h) * 128 + half * 64 + v)) * 128 + d] = accS[dt][reg];
    }
  }
}

// ---- RMSNorm over DV * norm_w * silu(z) -> yn bf16 ----
__global__ __launch_bounds__(256)
void rms_silu(const unsigned short* __restrict__ y, const unsigned short* __restrict__ qkvz,
              const float* __restrict__ nw, unsigned short* __restrict__ yn) {
  int m = blockIdx.x;
  int t = threadIdx.x;
  int head = t >> 3, oct = t & 7;
  int vb = head * 128 + oct * 16;
  const unsigned short* yp = y + (size_t)m * 4096 + vb;
  float yy[16];
  short8 y0 = *(const short8*)yp, y1 = *(const short8*)(yp + 8);
#pragma unroll
  for (int e = 0; e < 8; e++) { yy[e] = b2f((unsigned short)y0[e]); yy[8 + e] = b2f((unsigned short)y1[e]); }
  float ss = 0.f;
#pragma unroll
  for (int e = 0; e < 16; e++) ss += yy[e] * yy[e];
  ss += __shfl_xor(ss, 1); ss += __shfl_xor(ss, 2); ss += __shfl_xor(ss, 4);
  float rinv = rsqrtf(ss * (1.f / 128.f) + 1e-6f);
  const unsigned short* zp = qkvz + (size_t)m * NP + 8192 + vb;
  short8 z0 = *(const short8*)zp, z1 = *(const short8*)(zp + 8);
  short8 o0, o1;
#pragma unroll
  for (int e = 0; e < 8; e++) {
    float z = b2f((unsigned short)z0[e]);
    float v = nw[oct * 16 + e] * yy[e] * rinv * (z / (1.f + expf(-z)));
    o0[e] = (short)f2b(v);
    z = b2f((unsigned short)z1[e]);
    v = nw[oct * 16 + 8 + e] * yy[8 + e] * rinv * (z / (1.f + expf(-z)));
    o1[e] = (short)f2b(v);
  }
  unsigned short* op = yn + (size_t)m * 4096 + vb;
  *(short8*)op = o0;
  *(short8*)(op + 8) = o1;
}

extern "C" void kernel_launch(void* const* d_in, const int* in_sizes, int n_in,
                              void* d_out, int out_size, void* d_ws, size_t ws_size,
                              hipStream_t stream) {
  if (ws_size < WS_NEED) return;  // guard: fail with clean absmax, not a fault

  const float* x     = (const float*)d_in[0];
  const float* Wqkv  = (const float*)d_in[1];
  const float* Wz    = (const float*)d_in[2];
  const float* Wa    = (const float*)d_in[3];
  const float* Wb    = (const float*)d_in[4];
  const float* convw = (const float*)d_in[5];
  const float* Alog  = (const float*)d_in[6];
  const float* dtb   = (const float*)d_in[7];
  const float* nw    = (const float*)d_in[8];
  const float* Wout  = (const float*)d_in[9];

  char* ws = (char*)d_ws;
  unsigned short* qkvz = (unsigned short*)(ws + OFF_QKVZ);
  unsigned short* xb   = (unsigned short*)(ws + OFF_XB);
  unsigned short* wcat = (unsigned short*)(ws + OFF_WCAT);
  unsigned short* qkvs = (unsigned short*)(ws + OFF_QKVS);
  unsigned short* ynb  = (unsigned short*)(ws + OFF_YN);
  unsigned short* wob  = (unsigned short*)(ws + OFF_WOB);
  float* gbuf          = (float*)(ws + OFF_G);
  float* bbuf          = (float*)(ws + OFF_BET);

  float* outp       = (float*)d_out;
  float* conv_state = outp + 8388608;             // B*S*H
  float* state      = outp + 8388608 + 131072;    // + B*CI*KW
  unsigned short* ybuf = (unsigned short*)d_out;  // y bf16 scratch over outp region

  castk<<<8192, 256, 0, stream>>>(x, xb, 2097152);
  prep_wcat<<<24832, 256, 0, stream>>>(Wqkv, Wz, Wa, Wb, wcat);

  dim3 g1(32, 97);
  gemm_bt<unsigned short><<<g1, 256, 0, stream>>>(xb, wcat, qkvz, 4096, NP, 2048);

  conv_silu_norm<<<4096, 256, 0, stream>>>(qkvz, convw, qkvs);
  conv_state_k<<<512, 256, 0, stream>>>(qkvz, conv_state);
  gb_kernel<<<1024, 256, 0, stream>>>(qkvz, Alog, dtb, gbuf, bbuf);

  scan_chunk<<<256, 256, 0, stream>>>(qkvs, gbuf, bbuf, ybuf, state);

  rms_silu<<<4096, 256, 0, stream>>>(ybuf, qkvz, nw, ynb);
  castk<<<8192, 256, 0, stream>>>(Wout, wob, 2097152);

  dim3 g2(32, 16);
  gemm_bt<float><<<g2, 256, 0, stream>>>(ynb, wob, outp, 4096, 2048, 4096);
}

// Round 5
// 811.861 us; speedup vs baseline: 1.4309x; 1.0711x over previous
//
#include <hip/hip_runtime.h>
#include <cstdint>
#include <cstddef>

typedef __attribute__((ext_vector_type(8))) short short8;
typedef __attribute__((ext_vector_type(4))) short short4v;
typedef __attribute__((ext_vector_type(4))) float float4v;

#define DEV static __device__ __forceinline__

DEV float b2f(unsigned short u) { return __uint_as_float(((unsigned int)u) << 16); }
DEV unsigned short f2b(float f) {
  unsigned int u = __float_as_uint(f);
  u = (u + 0x7fffu + ((u >> 16) & 1u)) >> 16;
  return (unsigned short)u;
}

#define MFMA32(a, b, c) __builtin_amdgcn_mfma_f32_16x16x32_bf16(a, b, c, 0, 0, 0)

// ---- problem sizes ----
static constexpr int NP   = 12416;  // qkvz stride: 8192 qkv + 4096 z + 32 a + 32 b + 64 pad
static constexpr int NPAD = 12544;  // wcat rows padded to 49*256 for 256-tile GEMM

// ---- ws layout (bytes), lifetime-overlaid; peak ~162 MB ----
static constexpr size_t OFF_QKVZ = 0;
static constexpr size_t SZ_QKVZ  = (size_t)4096*NP*2;        // 101,711,872
static constexpr size_t OFF_XB   = SZ_QKVZ;
static constexpr size_t SZ_XB    = (size_t)4096*2048*2;      // 16,777,216
static constexpr size_t OFF_WCAT = OFF_XB + SZ_XB;
static constexpr size_t SZ_WCAT  = (size_t)NPAD*2048*2;      // 51,380,224
static constexpr size_t OFF_QKVS = OFF_XB;                   // overlays xb+wcat after GEMM1
static constexpr size_t SZ_QKVS  = (size_t)4096*8192*2;      // 67,108,864
static constexpr size_t OFF_G    = OFF_XB + SZ_QKVS;         // fits in gap before wcat end
static constexpr size_t OFF_BET  = OFF_G + (size_t)4096*32*4;
static constexpr size_t OFF_YN   = OFF_XB;                   // after scan
static constexpr size_t SZ_YN    = (size_t)4096*4096*2;
static constexpr size_t OFF_WOB  = OFF_YN + SZ_YN;
static constexpr size_t WS_NEED  = OFF_WCAT + SZ_WCAT;       // 169,869,312

// ---- helpers ----
DEV void gl16(const unsigned short* g, char* l) {
  __builtin_amdgcn_global_load_lds((const __attribute__((address_space(1))) unsigned int*)g,
                                   (__attribute__((address_space(3))) unsigned int*)l,
                                   16, 0, 0);
}

DEV void store_out(unsigned short* C, size_t off, float v) { C[off] = f2b(v); }
DEV void store_out(float* C, size_t off, float v)          { C[off] = v; }

// ---- generic cast fp32 -> bf16 (n multiple of 4) ----
__global__ void castk(const float* __restrict__ in, unsigned short* __restrict__ out, int n4) {
  int idx = blockIdx.x * 256 + threadIdx.x;
  if (idx >= n4) return;
  float4v v = ((const float4v*)in)[idx];
  short4v o;
  o[0] = (short)f2b(v[0]); o[1] = (short)f2b(v[1]);
  o[2] = (short)f2b(v[2]); o[3] = (short)f2b(v[3]);
  ((short4v*)out)[idx] = o;
}

// ---- build concatenated weight [12544][2048] bf16 ----
__global__ void prep_wcat(const float* __restrict__ Wqkv, const float* __restrict__ Wz,
                          const float* __restrict__ Wa, const float* __restrict__ Wb,
                          unsigned short* __restrict__ Wcat) {
  size_t e4 = (size_t)blockIdx.x * 256 + threadIdx.x;
  if (e4 >= (size_t)NPAD * 2048 / 4) return;
  size_t e = e4 * 4;
  int row = (int)(e >> 11);
  int col = (int)(e & 2047);
  float4v v;
  if (row < 8192)       v = *(const float4v*)&Wqkv[(size_t)row * 2048 + col];
  else if (row < 12288) v = *(const float4v*)&Wz[(size_t)(row - 8192) * 2048 + col];
  else if (row < 12320) v = *(const float4v*)&Wa[(size_t)(row - 12288) * 2048 + col];
  else if (row < 12352) v = *(const float4v*)&Wb[(size_t)(row - 12320) * 2048 + col];
  else                  v = (float4v){0.f, 0.f, 0.f, 0.f};
  short4v o;
  o[0] = (short)f2b(v[0]); o[1] = (short)f2b(v[1]);
  o[2] = (short)f2b(v[2]); o[3] = (short)f2b(v[3]);
  *(short4v*)&Wcat[e] = o;
}

// ================= 256x256 phase-interleaved bf16 MFMA GEMM =================
// C[M][NC] = A[M][K] @ B[N][K]^T. 512 thr = 8 waves (2M x 4N), BK=64,
// LDS 128KB (A/B double-buffered, XOR-swizzled via pre-swizzled global src).
// 4 phases/K-tile: {ds_read frags; 2x global_load_lds prefetch; setprio(1);
// 16 MFMA; setprio(0); s_barrier}; single vmcnt(0) at phase 4.
#define PHASE_MFMA(mh, nh, bvv)                                              \
  _Pragma("unroll") for (int mi = 0; mi < 4; mi++)                           \
  _Pragma("unroll") for (int nn = 0; nn < 2; nn++)                           \
  _Pragma("unroll") for (int ks = 0; ks < 2; ks++)                           \
    acc[(mh)*4 + mi][(nh)*2 + nn] =                                          \
        MFMA32(av[mi*2 + ks], bvv[nn*2 + ks], acc[(mh)*4 + mi][(nh)*2 + nn]);

template <typename OutT>
__global__ __launch_bounds__(512, 2)
void gemm256(const unsigned short* __restrict__ A, const unsigned short* __restrict__ B,
             OutT* __restrict__ C, int K, int nbn, int NC) {
  __shared__ __align__(16) unsigned short smem[65536];  // 128 KiB
  char* sm = (char*)smem;
  const int t = threadIdx.x;
  // bijective XCD swizzle (gridDim.x % 8 == 0)
  const int cpx = gridDim.x >> 3;
  int wg = blockIdx.x;
  wg = (wg & 7) * cpx + (wg >> 3);
  const int bm = wg / nbn, bn = wg % nbn;

  const int wv = t >> 6, lane = t & 63;
  const int l16 = lane & 15, lg = lane >> 4;
  const int wm = (wv >> 2) * 128;  // M-group (2)
  const int wn = (wv & 3) * 64;    // N-group (4)

  // staging: round r covers LDS bytes [r*8192 + t*16]; linear dest,
  // source column pre-swizzled so that swizzled ds_reads see (row,col).
  size_t aoff[4], boff[4];
#pragma unroll
  for (int r = 0; r < 4; r++) {
    int L = r * 8192 + t * 16;
    int row = L >> 7;
    int col = ((L & 127) ^ ((row & 7) << 4)) >> 1;
    aoff[r] = (size_t)(bm * 256 + row) * K + col;
    boff[r] = (size_t)(bn * 256 + row) * K + col;
  }

  float4v acc[8][4] = {};
  const int NKT = K >> 6;

  // prologue: stage K-tile 0 into buf 0
#pragma unroll
  for (int r = 0; r < 4; r++) {
    gl16(A + aoff[r], sm + r * 8192 + t * 16);
    gl16(B + boff[r], sm + 65536 + r * 8192 + t * 16);
  }
  asm volatile("s_waitcnt vmcnt(0)" ::: "memory");
  __builtin_amdgcn_s_barrier();

  for (int kt = 0; kt < NKT; kt++) {
    const int cur = kt & 1;
    const int abase = cur * 32768;
    const int bbase = 65536 + cur * 32768;
    const int nb = (cur ^ 1) * 32768;
    const bool pf = (kt + 1 < NKT);
    const size_t koff = (size_t)(kt + 1) * 64;
    short8 av[8], bv0[4], bv1[4];

    // ---- phase 0: (mh0, nh0) ----
#pragma unroll
    for (int mi = 0; mi < 4; mi++)
#pragma unroll
      for (int ks = 0; ks < 2; ks++) {
        int row = wm + mi * 16 + l16;
        av[mi * 2 + ks] = *(const short8*)(sm + abase + row * 128 +
                                           ((ks * 64 + lg * 16) ^ ((row & 7) << 4)));
      }
#pragma unroll
    for (int nn = 0; nn < 2; nn++)
#pragma unroll
      for (int ks = 0; ks < 2; ks++) {
        int row = wn + nn * 16 + l16;
        bv0[nn * 2 + ks] = *(const short8*)(sm + bbase + row * 128 +
                                            ((ks * 64 + lg * 16) ^ ((row & 7) << 4)));
      }
    if (pf) {
      gl16(A + aoff[0] + koff, sm + nb + t * 16);
      gl16(B + boff[0] + koff, sm + 65536 + nb + t * 16);
    }
    __builtin_amdgcn_s_setprio(1);
    PHASE_MFMA(0, 0, bv0)
    __builtin_amdgcn_s_setprio(0);
    __builtin_amdgcn_s_barrier();

    // ---- phase 1: (mh0, nh1) ----
#pragma unroll
    for (int nn = 0; nn < 2; nn++)
#pragma unroll
      for (int ks = 0; ks < 2; ks++) {
        int row = wn + 32 + nn * 16 + l16;
        bv1[nn * 2 + ks] = *(const short8*)(sm + bbase + row * 128 +
                                            ((ks * 64 + lg * 16) ^ ((row & 7) << 4)));
      }
    if (pf) {
      gl16(A + aoff[1] + koff, sm + nb + 8192 + t * 16);
      gl16(B + boff[1] + koff, sm + 65536 + nb + 8192 + t * 16);
    }
    __builtin_amdgcn_s_setprio(1);
    PHASE_MFMA(0, 1, bv1)
    __builtin_amdgcn_s_setprio(0);
    __builtin_amdgcn_s_barrier();

    // ---- phase 2: (mh1, nh1) ----
#pragma unroll
    for (int mi = 0; mi < 4; mi++)
#pragma unroll
      for (int ks = 0; ks < 2; ks++) {
        int row = wm + 64 + mi * 16 + l16;
        av[mi * 2 + ks] = *(const short8*)(sm + abase + row * 128 +
                                           ((ks * 64 + lg * 16) ^ ((row & 7) << 4)));
      }
    if (pf) {
      gl16(A + aoff[2] + koff, sm + nb + 16384 + t * 16);
      gl16(B + boff[2] + koff, sm + 65536 + nb + 16384 + t * 16);
    }
    __builtin_amdgcn_s_setprio(1);
    PHASE_MFMA(1, 1, bv1)
    __builtin_amdgcn_s_setprio(0);
    __builtin_amdgcn_s_barrier();

    // ---- phase 3: (mh1, nh0) ----
    if (pf) {
      gl16(A + aoff[3] + koff, sm + nb + 24576 + t * 16);
      gl16(B + boff[3] + koff, sm + 65536 + nb + 24576 + t * 16);
    }
    __builtin_amdgcn_s_setprio(1);
    PHASE_MFMA(1, 0, bv0)
    __builtin_amdgcn_s_setprio(0);
    asm volatile("s_waitcnt vmcnt(0)" ::: "memory");  // next K-tile fully arrived
    __builtin_amdgcn_s_barrier();
    __builtin_amdgcn_sched_barrier(0);
  }

  // epilogue
#pragma unroll
  for (int m = 0; m < 8; m++) {
    int row0 = bm * 256 + wm + m * 16 + lg * 4;
#pragma unroll
    for (int n = 0; n < 4; n++) {
      int col = bn * 256 + wn + n * 16 + l16;
      if (col < NC) {
#pragma unroll
        for (int rr = 0; rr < 4; rr++)
          store_out(C, (size_t)(row0 + rr) * NC + col, acc[m][n][rr]);
      }
    }
  }
}

// ---- conv(KW=4) + silu + q/k L2-norm ----
__global__ __launch_bounds__(256)
void conv_silu_norm(const unsigned short* __restrict__ qkvz, const float* __restrict__ conv_w,
                    unsigned short* __restrict__ qkvs) {
  const int m = blockIdx.x;           // b*S + s
  const int sloc = m & 1023;
  const int t = threadIdx.x;
  const int c0 = t * 32;
  float out[32];
#pragma unroll
  for (int cc = 0; cc < 32; cc += 8) {
    const int c = c0 + cc;
    float a8[8] = {0.f, 0.f, 0.f, 0.f, 0.f, 0.f, 0.f, 0.f};
#pragma unroll
    for (int j = 0; j < 4; j++) {
      const int sj = sloc - 3 + j;
      if (sj >= 0) {
        short8 v8 = *(const short8*)&qkvz[(size_t)(m - 3 + j) * NP + c];
#pragma unroll
        for (int e = 0; e < 8; e++)
          a8[e] = fmaf(b2f((unsigned short)v8[e]), conv_w[(c + e) * 4 + j], a8[e]);
      }
    }
#pragma unroll
    for (int e = 0; e < 8; e++) { float x = a8[e]; out[cc + e] = x * (1.f / (1.f + expf(-x))); }
  }
  if (c0 < 4096) {  // q or k head: L2 normalize over 128 ch (4 threads/head)
    float ss = 0.f;
#pragma unroll
    for (int e = 0; e < 32; e++) ss += out[e] * out[e];
    ss += __shfl_xor(ss, 1);
    ss += __shfl_xor(ss, 2);
    float sc = rsqrtf(ss + 1e-6f);
    if (c0 < 2048) sc *= 0.08838834764831845f;  // * DK^-0.5 for q
#pragma unroll
    for (int e = 0; e < 32; e++) out[e] *= sc;
  }
  const size_t ob = (size_t)m * 8192 + c0;
#pragma unroll
  for (int cc = 0; cc < 32; cc += 8) {
    short8 w;
#pragma unroll
    for (int e = 0; e < 8; e++) w[e] = (short)f2b(out[cc + e]);
    *(short8*)&qkvs[ob + cc] = w;
  }
}

// ---- conv_state output: (B,CI,KW) fp32 from pre-conv qkv ----
__global__ void conv_state_k(const unsigned short* __restrict__ qkvz, float* __restrict__ cs) {
  int idx = blockIdx.x * 256 + threadIdx.x;  // < 131072 = 4*8192*4
  int b = idx >> 15;
  int rem = idx & 32767;
  int c = rem >> 2;
  int j = rem & 3;
  cs[idx] = b2f(qkvz[(size_t)(b * 1024 + 1020 + j) * NP + c]);
}

// ---- g / beta from a,b columns ----
__global__ void gb_kernel(const unsigned short* __restrict__ qkvz, const float* __restrict__ A_log,
                          const float* __restrict__ dt_bias, float* __restrict__ g,
                          float* __restrict__ bet) {
  int idx = blockIdx.x * 256 + threadIdx.x;  // < 4096*64
  int m = idx >> 6, n = idx & 63;
  if (n < 32) {
    float a = b2f(qkvz[(size_t)m * NP + 12288 + n]) + dt_bias[n];
    float sp = (a > 20.f) ? a : log1pf(expf(a));
    g[m * 32 + n] = -expf(A_log[n]) * sp;
  } else {
    int nn = n - 32;
    float bb = b2f(qkvz[(size_t)m * NP + 12320 + nn]);
    bet[m * 32 + nn] = 1.f / (1.f + expf(-bb));
  }
}

// ---- chunked delta-rule scan (UT transform), C=64, MFMA throughout ----
__global__ __launch_bounds__(256)
void scan_chunk(const unsigned short* __restrict__ qkvs, const float* __restrict__ g,
                const float* __restrict__ bet, unsigned short* __restrict__ y,
                float* __restrict__ state_out) {
  __shared__ __align__(16) unsigned short Kb[64][128];
  __shared__ __align__(16) unsigned short Qb[64][128];
  __shared__ __align__(16) unsigned short Sb[64][128];
  __shared__ __align__(16) unsigned short Ktt[128][64];
  __shared__ __align__(16) unsigned short Mb[64][64];
  __shared__ __align__(16) unsigned short Nb[64][64];
  __shared__ __align__(16) unsigned short Dbf[64][64];
  __shared__ __align__(16) unsigned short Vt[64][64];   // also reused as obuf
  __shared__ __align__(16) unsigned short Tb[4][16][16];
  __shared__ __align__(16) unsigned short rtmp[64][16];
  __shared__ float Gar[64];
  __shared__ float gamv[64];
  __shared__ float barr[64];
  __shared__ float gcs[2];

  const int bid = blockIdx.x;
  const int b = bid >> 6;
  const int h = (bid >> 1) & 31;
  const int half = bid & 1;
  const int hk = h >> 1;
  const int t = threadIdx.x;
  const int wv = t >> 6, lane = t & 63;
  const int l16 = lane & 15, lg = lane >> 4;
  const int bS = b << 10;

  float4v accS[8] = {};
  for (int idx = t; idx < 64 * 128; idx += 256) (&Sb[0][0])[idx] = 0;

  for (int ch = 0; ch < 16; ch++) {
    const int s0 = ch << 6;
    // ---- phase 1: stage Kb, Qb (swizzled via source permutation), Vt, g/beta ----
    {
#pragma unroll
      for (int rep = 0; rep < 4; rep++) {
        int rb = wv * 16 + rep * 4;
        int i = rb + (lane >> 4);
        int cg = (lane & 15) ^ (i & 7);
        const unsigned short* gk = qkvs + (size_t)(bS + s0 + i) * 8192 + 2048 + hk * 128 + cg * 8;
        gl16(gk, (char*)(&Kb[rb][0] + lane * 8));
        const unsigned short* gq = qkvs + (size_t)(bS + s0 + i) * 8192 + hk * 128 + cg * 8;
        gl16(gq, (char*)(&Qb[rb][0] + lane * 8));
      }
    }
    {
      int tt = t >> 2, q4 = t & 3;
      const unsigned short* gv = qkvs + (size_t)(bS + s0 + tt) * 8192 + 4096 + h * 128 + half * 64 + q4 * 16;
      short8 v0 = *(const short8*)gv;
      short8 v1 = *(const short8*)(gv + 8);
#pragma unroll
      for (int e = 0; e < 8; e++) {
        int v = q4 * 16 + e;
        Vt[v][tt ^ ((v & 7) << 3)] = (unsigned short)v0[e];
        v = q4 * 16 + 8 + e;
        Vt[v][tt ^ ((v & 7) << 3)] = (unsigned short)v1[e];
      }
    }
    if (t < 64) {
      float gt = g[(bS + s0 + t) * 32 + h];
      float bt = bet[(bS + s0 + t) * 32 + h];
#pragma unroll
      for (int d = 1; d < 64; d <<= 1) {
        float o = __shfl_up(gt, d);
        if (t >= d) gt += o;
      }
      Gar[t] = gt;
      gamv[t] = __expf(gt);
      barr[t] = bt;
      if (t == 63) { gcs[0] = gt; gcs[1] = __expf(gt); }
    }
    __syncthreads();

    // ---- phase 2: KK^T -> Mb, QK^T -> Nb; build Ktt ----
    {
      float4v aK[4] = {}, aQ[4] = {};
      const int arow = wv * 16 + l16;
      const int asw = (arow & 7) << 3;
#pragma unroll
      for (int kk = 0; kk < 4; kk++) {
        short8 av = *(const short8*)&Kb[arow][(kk * 32 + lg * 8) ^ asw];
        short8 aq = *(const short8*)&Qb[arow][(kk * 32 + lg * 8) ^ asw];
#pragma unroll
        for (int j = 0; j < 4; j++) {
          int brow = j * 16 + l16;
          short8 bv = *(const short8*)&Kb[brow][(kk * 32 + lg * 8) ^ ((brow & 7) << 3)];
          aK[j] = MFMA32(av, bv, aK[j]);
          aQ[j] = MFMA32(aq, bv, aQ[j]);
        }
      }
#pragma unroll
      for (int j = 0; j < 4; j++) {
#pragma unroll
        for (int reg = 0; reg < 4; reg++) {
          int tt = wv * 16 + lg * 4 + reg;
          int ii = j * 16 + l16;
          float sc = __expf(Gar[tt] - Gar[ii]);
          float mv = (ii < tt) ? aK[j][reg] * barr[tt] * sc : 0.f;
          float nv = (ii <= tt) ? aQ[j][reg] * sc : 0.f;
          Mb[tt][(ii ^ ((tt & 7) << 3))] = f2b(mv);
          Nb[tt][(ii ^ ((tt & 7) << 3))] = f2b(nv);
        }
      }
    }
    {
      int i = t >> 2, q4 = t & 3;
      float sc = __expf(gcs[0] - Gar[i]);
      int isw = (i & 7) << 3;
#pragma unroll
      for (int e8 = 0; e8 < 4; e8++) {
        int d0 = q4 * 32 + e8 * 8;
        short8 kv = *(const short8*)&Kb[i][d0 ^ isw];
#pragma unroll
        for (int e = 0; e < 8; e++) {
          int d = d0 + e;
          Ktt[d][i ^ ((d & 7) << 3)] = f2b(b2f((unsigned short)kv[e]) * sc);
        }
      }
    }
    __syncthreads();

    // ---- phase 3: P0t = S0 K^T; RHS -> Dbf; T-inverse -> Tb ----
    {
      float4v acc[4] = {};
      const int arow = wv * 16 + l16;  // v
      const int asw = (arow & 7) << 3;
#pragma unroll
      for (int kk = 0; kk < 4; kk++) {
        short8 av = *(const short8*)&Sb[arow][(kk * 32 + lg * 8) ^ asw];
#pragma unroll
        for (int j = 0; j < 4; j++) {
          int brow = j * 16 + l16;  // t
          short8 bv = *(const short8*)&Kb[brow][(kk * 32 + lg * 8) ^ ((brow & 7) << 3)];
          acc[j] = MFMA32(av, bv, acc[j]);
        }
      }
#pragma unroll
      for (int j = 0; j < 4; j++) {
#pragma unroll
        for (int reg = 0; reg < 4; reg++) {
          int v = wv * 16 + lg * 4 + reg;
          int tt = j * 16 + l16;
          float vtv = b2f(Vt[v][tt ^ ((v & 7) << 3)]);
          float val = barr[tt] * (vtv - gamv[tt] * acc[j][reg]);
          Dbf[v][tt ^ ((v & 7) << 3)] = f2b(val);
        }
      }
    }
    {
      // T-inverse of diagonal block wv (unit lower)
      float Lrow[16];
#pragma unroll
      for (int i = 0; i < 16; i++)
        Lrow[i] = b2f(Mb[wv * 16 + l16][((wv * 16 + i) ^ ((l16 & 7) << 3))]);
      float Tc[16];
#pragma unroll
      for (int i = 0; i < 16; i++) Tc[i] = (i == l16) ? 1.f : 0.f;
#pragma unroll
      for (int tt = 1; tt < 16; tt++) {
        float s = 0.f;
#pragma unroll
        for (int i = 0; i < 16; i++) {
          if (i < tt)
            s += __int_as_float(__builtin_amdgcn_readlane(__float_as_int(Lrow[i]), tt)) * Tc[i];
        }
        Tc[tt] = ((tt == l16) ? 1.f : 0.f) - s;
      }
      if (lane < 16) {
#pragma unroll
        for (int tt = 0; tt < 16; tt++) Tb[wv][tt][l16] = f2b(Tc[tt]);
      }
    }
    __syncthreads();

    // ---- phase 4: block forward substitution, D = (I+M)^{-1} RHS ----
    {
      short8 a = (short8)(short)0, bT = (short8)(short)0;
      const int arow = wv * 16 + l16;
      if (lg < 2) {
        a = *(const short8*)&Dbf[arow][((lg * 8) ^ ((arow & 7) << 3))];
        bT = *(const short8*)&Tb[0][l16][lg * 8];
      }
      float4v acc0 = {};
      acc0 = MFMA32(a, bT, acc0);
      __syncthreads();
#pragma unroll
      for (int reg = 0; reg < 4; reg++) {
        int v = wv * 16 + lg * 4 + reg;
        Dbf[v][(l16 ^ ((v & 7) << 3))] = f2b(acc0[reg]);
      }
    }
    __syncthreads();
#pragma unroll
    for (int s = 1; s < 4; s++) {
      float4v acc = {};
      const int arow = wv * 16 + l16;
      const int mrow = s * 16 + l16;
#pragma unroll
      for (int j = 0; j < 3; j++) {
        if (j < s) {
          short8 a = (short8)(short)0, bM = (short8)(short)0;
          if (lg < 2) {
            a  = *(const short8*)&Dbf[arow][((j * 16 + lg * 8) ^ ((arow & 7) << 3))];
            bM = *(const short8*)&Mb[mrow][((j * 16 + lg * 8) ^ ((mrow & 7) << 3))];
          }
          acc = MFMA32(a, bM, acc);
        }
      }
#pragma unroll
      for (int reg = 0; reg < 4; reg++) {
        int v = wv * 16 + lg * 4 + reg;
        float rt = b2f(Dbf[v][((s * 16 + l16) ^ ((v & 7) << 3))]);
        rtmp[v][l16] = f2b(rt - acc[reg]);
      }
      __syncthreads();
      short8 a2 = (short8)(short)0, bT = (short8)(short)0;
      if (lg < 2) {
        a2 = *(const short8*)&rtmp[wv * 16 + l16][lg * 8];
        bT = *(const short8*)&Tb[s][l16][lg * 8];
      }
      float4v acc2 = {};
      acc2 = MFMA32(a2, bT, acc2);
      __syncthreads();
#pragma unroll
      for (int reg = 0; reg < 4; reg++) {
        int v = wv * 16 + lg * 4 + reg;
        Dbf[v][((s * 16 + l16) ^ ((v & 7) << 3))] = f2b(acc2[reg]);
      }
      __syncthreads();
    }

    // ---- phase 5: O = diag(gam) Q S0^T + N D ----
    {
      float4v acc[4] = {};
      const int arow = wv * 16 + l16;  // t
      const int asw = (arow & 7) << 3;
#pragma unroll
      for (int kk = 0; kk < 4; kk++) {
        short8 aq = *(const short8*)&Qb[arow][(kk * 32 + lg * 8) ^ asw];
#pragma unroll
        for (int j = 0; j < 4; j++) {
          int brow = j * 16 + l16;  // v
          short8 bs = *(const short8*)&Sb[brow][(kk * 32 + lg * 8) ^ ((brow & 7) << 3)];
          acc[j] = MFMA32(aq, bs, acc[j]);
        }
      }
#pragma unroll
      for (int j = 0; j < 4; j++) {
#pragma unroll
        for (int reg = 0; reg < 4; reg++) {
          int tt = wv * 16 + lg * 4 + reg;
          acc[j][reg] *= gamv[tt];
        }
      }
#pragma unroll
      for (int kk = 0; kk < 2; kk++) {
        short8 an = *(const short8*)&Nb[arow][(kk * 32 + lg * 8) ^ asw];
#pragma unroll
        for (int j = 0; j < 4; j++) {
          int brow = j * 16 + l16;  // v
          short8 bd = *(const short8*)&Dbf[brow][(kk * 32 + lg * 8) ^ ((brow & 7) << 3)];
          acc[j] = MFMA32(an, bd, acc[j]);
        }
      }
      __syncthreads();  // Vt consumed; reuse as obuf
#pragma unroll
      for (int j = 0; j < 4; j++) {
#pragma unroll
        for (int reg = 0; reg < 4; reg++) {
          int tt = wv * 16 + lg * 4 + reg;
          int v = j * 16 + l16;
          Vt[tt][v ^ ((tt & 7) << 3)] = f2b(acc[j][reg]);
        }
      }
    }
    __syncthreads();
    {
      int tt = t >> 2, q4 = t & 3;
      int sw = (tt & 7) << 3;
      unsigned short* yg = y + (size_t)(bS + s0 + tt) * 4096 + h * 128 + half * 64 + q4 * 16;
      short8 o0 = *(const short8*)&Vt[tt][(q4 * 16) ^ sw];
      short8 o1 = *(const short8*)&Vt[tt][(q4 * 16 + 8) ^ sw];
      *(short8*)yg = o0;
      *(short8*)(yg + 8) = o1;
    }

    // ---- phase 6: state update S = gamC * S + D^T Ktt ----
    {
      float gC = gcs[1];
#pragma unroll
      for (int dt = 0; dt < 8; dt++)
#pragma unroll
        for (int reg = 0; reg < 4; reg++) accS[dt][reg] *= gC;
      const int arow = wv * 16 + l16;  // v
      const int asw = (arow & 7) << 3;
#pragma unroll
      for (int kk = 0; kk < 2; kk++) {
        short8 ad = *(const short8*)&Dbf[arow][(kk * 32 + lg * 8) ^ asw];
#pragma unroll
        for (int dt = 0; dt < 8; dt++) {
          int brow = dt * 16 + l16;  // d
          short8 bk = *(const short8*)&Ktt[brow][(kk * 32 + lg * 8) ^ ((brow & 7) << 3)];
          accS[dt] = MFMA32(ad, bk, accS[dt]);
        }
      }
      __syncthreads();
#pragma unroll
      for (int dt = 0; dt < 8; dt++) {
#pragma unroll
        for (int reg = 0; reg < 4; reg++) {
          int v = wv * 16 + lg * 4 + reg;
          int d = dt * 16 + l16;
          Sb[v][d ^ ((v & 7) << 3)] = f2b(accS[dt][reg]);
        }
      }
    }
    __syncthreads();
  }

  // final state writeout (fp32)
#pragma unroll
  for (int dt = 0; dt < 8; dt++) {
#pragma unroll
    for (int reg = 0; reg < 4; reg++) {
      int v = wv * 16 + lg * 4 + reg;
      int d = dt * 16 + l16;
      state_out[((size_t)((b * 32 + h) * 128 + half * 64 + v)) * 128 + d] = accS[dt][reg];
    }
  }
}

// ---- RMSNorm over DV * norm_w * silu(z) -> yn bf16 ----
__global__ __launch_bounds__(256)
void rms_silu(const unsigned short* __restrict__ y, const unsigned short* __restrict__ qkvz,
              const float* __restrict__ nw, unsigned short* __restrict__ yn) {
  int m = blockIdx.x;
  int t = threadIdx.x;
  int head = t >> 3, oct = t & 7;
  int vb = head * 128 + oct * 16;
  const unsigned short* yp = y + (size_t)m * 4096 + vb;
  float yy[16];
  short8 y0 = *(const short8*)yp, y1 = *(const short8*)(yp + 8);
#pragma unroll
  for (int e = 0; e < 8; e++) { yy[e] = b2f((unsigned short)y0[e]); yy[8 + e] = b2f((unsigned short)y1[e]); }
  float ss = 0.f;
#pragma unroll
  for (int e = 0; e < 16; e++) ss += yy[e] * yy[e];
  ss += __shfl_xor(ss, 1); ss += __shfl_xor(ss, 2); ss += __shfl_xor(ss, 4);
  float rinv = rsqrtf(ss * (1.f / 128.f) + 1e-6f);
  const unsigned short* zp = qkvz + (size_t)m * NP + 8192 + vb;
  short8 z0 = *(const short8*)zp, z1 = *(const short8*)(zp + 8);
  short8 o0, o1;
#pragma unroll
  for (int e = 0; e < 8; e++) {
    float z = b2f((unsigned short)z0[e]);
    float v = nw[oct * 16 + e] * yy[e] * rinv * (z / (1.f + expf(-z)));
    o0[e] = (short)f2b(v);
    z = b2f((unsigned short)z1[e]);
    v = nw[oct * 16 + 8 + e] * yy[8 + e] * rinv * (z / (1.f + expf(-z)));
    o1[e] = (short)f2b(v);
  }
  unsigned short* op = yn + (size_t)m * 4096 + vb;
  *(short8*)op = o0;
  *(short8*)(op + 8) = o1;
}

extern "C" void kernel_launch(void* const* d_in, const int* in_sizes, int n_in,
                              void* d_out, int out_size, void* d_ws, size_t ws_size,
                              hipStream_t stream) {
  if (ws_size < WS_NEED) return;  // guard: fail with clean absmax, not a fault

  const float* x     = (const float*)d_in[0];
  const float* Wqkv  = (const float*)d_in[1];
  const float* Wz    = (const float*)d_in[2];
  const float* Wa    = (const float*)d_in[3];
  const float* Wb    = (const float*)d_in[4];
  const float* convw = (const float*)d_in[5];
  const float* Alog  = (const float*)d_in[6];
  const float* dtb   = (const float*)d_in[7];
  const float* nw    = (const float*)d_in[8];
  const float* Wout  = (const float*)d_in[9];

  char* ws = (char*)d_ws;
  unsigned short* qkvz = (unsigned short*)(ws + OFF_QKVZ);
  unsigned short* xb   = (unsigned short*)(ws + OFF_XB);
  unsigned short* wcat = (unsigned short*)(ws + OFF_WCAT);
  unsigned short* qkvs = (unsigned short*)(ws + OFF_QKVS);
  unsigned short* ynb  = (unsigned short*)(ws + OFF_YN);
  unsigned short* wob  = (unsigned short*)(ws + OFF_WOB);
  float* gbuf          = (float*)(ws + OFF_G);
  float* bbuf          = (float*)(ws + OFF_BET);

  float* outp       = (float*)d_out;
  float* conv_state = outp + 8388608;             // B*S*H
  float* state      = outp + 8388608 + 131072;    // + B*CI*KW
  unsigned short* ybuf = (unsigned short*)d_out;  // y bf16 scratch over outp region

  castk<<<8192, 256, 0, stream>>>(x, xb, 2097152);
  prep_wcat<<<25088, 256, 0, stream>>>(Wqkv, Wz, Wa, Wb, wcat);

  gemm256<unsigned short><<<784, 512, 0, stream>>>(xb, wcat, qkvz, 2048, 49, NP);

  conv_silu_norm<<<4096, 256, 0, stream>>>(qkvz, convw, qkvs);
  conv_state_k<<<512, 256, 0, stream>>>(qkvz, conv_state);
  gb_kernel<<<1024, 256, 0, stream>>>(qkvz, Alog, dtb, gbuf, bbuf);

  scan_chunk<<<256, 256, 0, stream>>>(qkvs, gbuf, bbuf, ybuf, state);

  rms_silu<<<4096, 256, 0, stream>>>(ybuf, qkvz, nw, ynb);
  castk<<<8192, 256, 0, stream>>>(Wout, wob, 2097152);

  gemm256<float><<<128, 512, 0, stream>>>(ynb, wob, outp, 4096, 8, 2048);
}

// Round 6
// 601.775 us; speedup vs baseline: 1.9304x; 1.3491x over previous
//
#include <hip/hip_runtime.h>
#include <cstdint>
#include <cstddef>

typedef __attribute__((ext_vector_type(8))) short short8;
typedef __attribute__((ext_vector_type(4))) short short4v;
typedef __attribute__((ext_vector_type(4))) float float4v;

#define DEV static __device__ __forceinline__

DEV float b2f(unsigned short u) { return __uint_as_float(((unsigned int)u) << 16); }
DEV unsigned short f2b(float f) {
  unsigned int u = __float_as_uint(f);
  u = (u + 0x7fffu + ((u >> 16) & 1u)) >> 16;
  return (unsigned short)u;
}

#define MFMA32(a, b, c) __builtin_amdgcn_mfma_f32_16x16x32_bf16(a, b, c, 0, 0, 0)

// ---- problem sizes ----
static constexpr int NP   = 12416;  // qkvz stride: 8192 qkv + 4096 z + 32 a + 32 b + 64 pad
static constexpr int NPAD = 12544;  // wcat rows padded to 49*256 for 256-tile GEMM

// ---- ws layout (bytes), lifetime-overlaid; peak ~162 MB ----
static constexpr size_t OFF_QKVZ = 0;
static constexpr size_t SZ_QKVZ  = (size_t)4096*NP*2;        // 101,711,872
static constexpr size_t OFF_XB   = SZ_QKVZ;
static constexpr size_t SZ_XB    = (size_t)4096*2048*2;      // 16,777,216
static constexpr size_t OFF_WCAT = OFF_XB + SZ_XB;
static constexpr size_t SZ_WCAT  = (size_t)NPAD*2048*2;      // 51,380,224
static constexpr size_t OFF_QKVS = OFF_XB;                   // overlays xb+wcat after GEMM1
static constexpr size_t SZ_QKVS  = (size_t)4096*8192*2;      // 67,108,864
static constexpr size_t OFF_G    = OFF_XB + SZ_QKVS;         // fits in gap before wcat end
static constexpr size_t OFF_BET  = OFF_G + (size_t)4096*32*4;
static constexpr size_t OFF_YN   = OFF_XB;                   // after scan
static constexpr size_t SZ_YN    = (size_t)4096*4096*2;
static constexpr size_t OFF_WOB  = OFF_YN + SZ_YN;
static constexpr size_t WS_NEED  = OFF_WCAT + SZ_WCAT;       // 169,869,312

// ---- helpers ----
DEV void gl16(const unsigned short* g, char* l) {
  __builtin_amdgcn_global_load_lds((const __attribute__((address_space(1))) unsigned int*)g,
                                   (__attribute__((address_space(3))) unsigned int*)l,
                                   16, 0, 0);
}

DEV void store_out(unsigned short* C, size_t off, float v) { C[off] = f2b(v); }
DEV void store_out(float* C, size_t off, float v)          { C[off] = v; }

// ---- generic cast fp32 -> bf16 (n multiple of 4) ----
__global__ void castk(const float* __restrict__ in, unsigned short* __restrict__ out, int n4) {
  int idx = blockIdx.x * 256 + threadIdx.x;
  if (idx >= n4) return;
  float4v v = ((const float4v*)in)[idx];
  short4v o;
  o[0] = (short)f2b(v[0]); o[1] = (short)f2b(v[1]);
  o[2] = (short)f2b(v[2]); o[3] = (short)f2b(v[3]);
  ((short4v*)out)[idx] = o;
}

// ---- build concatenated weight [12544][2048] bf16 ----
__global__ void prep_wcat(const float* __restrict__ Wqkv, const float* __restrict__ Wz,
                          const float* __restrict__ Wa, const float* __restrict__ Wb,
                          unsigned short* __restrict__ Wcat) {
  size_t e4 = (size_t)blockIdx.x * 256 + threadIdx.x;
  if (e4 >= (size_t)NPAD * 2048 / 4) return;
  size_t e = e4 * 4;
  int row = (int)(e >> 11);
  int col = (int)(e & 2047);
  float4v v;
  if (row < 8192)       v = *(const float4v*)&Wqkv[(size_t)row * 2048 + col];
  else if (row < 12288) v = *(const float4v*)&Wz[(size_t)(row - 8192) * 2048 + col];
  else if (row < 12320) v = *(const float4v*)&Wa[(size_t)(row - 12288) * 2048 + col];
  else if (row < 12352) v = *(const float4v*)&Wb[(size_t)(row - 12320) * 2048 + col];
  else                  v = (float4v){0.f, 0.f, 0.f, 0.f};
  short4v o;
  o[0] = (short)f2b(v[0]); o[1] = (short)f2b(v[1]);
  o[2] = (short)f2b(v[2]); o[3] = (short)f2b(v[3]);
  *(short4v*)&Wcat[e] = o;
}

// ================= 256x256 phase-interleaved bf16 MFMA GEMM =================
#define PHASE_MFMA(mh, nh, bvv)                                              \
  _Pragma("unroll") for (int mi = 0; mi < 4; mi++)                           \
  _Pragma("unroll") for (int nn = 0; nn < 2; nn++)                           \
  _Pragma("unroll") for (int ks = 0; ks < 2; ks++)                           \
    acc[(mh)*4 + mi][(nh)*2 + nn] =                                          \
        MFMA32(av[mi*2 + ks], bvv[nn*2 + ks], acc[(mh)*4 + mi][(nh)*2 + nn]);

template <typename OutT>
__global__ __launch_bounds__(512, 2)
void gemm256(const unsigned short* __restrict__ A, const unsigned short* __restrict__ B,
             OutT* __restrict__ C, int K, int nbn, int NC) {
  __shared__ __align__(16) unsigned short smem[65536];  // 128 KiB
  char* sm = (char*)smem;
  const int t = threadIdx.x;
  const int cpx = gridDim.x >> 3;
  int wg = blockIdx.x;
  wg = (wg & 7) * cpx + (wg >> 3);
  const int bm = wg / nbn, bn = wg % nbn;

  const int wv = t >> 6, lane = t & 63;
  const int l16 = lane & 15, lg = lane >> 4;
  const int wm = (wv >> 2) * 128;
  const int wn = (wv & 3) * 64;

  size_t aoff[4], boff[4];
#pragma unroll
  for (int r = 0; r < 4; r++) {
    int L = r * 8192 + t * 16;
    int row = L >> 7;
    int col = ((L & 127) ^ ((row & 7) << 4)) >> 1;
    aoff[r] = (size_t)(bm * 256 + row) * K + col;
    boff[r] = (size_t)(bn * 256 + row) * K + col;
  }

  float4v acc[8][4] = {};
  const int NKT = K >> 6;

#pragma unroll
  for (int r = 0; r < 4; r++) {
    gl16(A + aoff[r], sm + r * 8192 + t * 16);
    gl16(B + boff[r], sm + 65536 + r * 8192 + t * 16);
  }
  asm volatile("s_waitcnt vmcnt(0)" ::: "memory");
  __builtin_amdgcn_s_barrier();

  for (int kt = 0; kt < NKT; kt++) {
    const int cur = kt & 1;
    const int abase = cur * 32768;
    const int bbase = 65536 + cur * 32768;
    const int nb = (cur ^ 1) * 32768;
    const bool pf = (kt + 1 < NKT);
    const size_t koff = (size_t)(kt + 1) * 64;
    short8 av[8], bv0[4], bv1[4];

    // ---- phase 0: (mh0, nh0) ----
#pragma unroll
    for (int mi = 0; mi < 4; mi++)
#pragma unroll
      for (int ks = 0; ks < 2; ks++) {
        int row = wm + mi * 16 + l16;
        av[mi * 2 + ks] = *(const short8*)(sm + abase + row * 128 +
                                           ((ks * 64 + lg * 16) ^ ((row & 7) << 4)));
      }
#pragma unroll
    for (int nn = 0; nn < 2; nn++)
#pragma unroll
      for (int ks = 0; ks < 2; ks++) {
        int row = wn + nn * 16 + l16;
        bv0[nn * 2 + ks] = *(const short8*)(sm + bbase + row * 128 +
                                            ((ks * 64 + lg * 16) ^ ((row & 7) << 4)));
      }
    if (pf) {
      gl16(A + aoff[0] + koff, sm + nb + t * 16);
      gl16(B + boff[0] + koff, sm + 65536 + nb + t * 16);
    }
    __builtin_amdgcn_s_setprio(1);
    PHASE_MFMA(0, 0, bv0)
    __builtin_amdgcn_s_setprio(0);
    __builtin_amdgcn_s_barrier();

    // ---- phase 1: (mh0, nh1) ----
#pragma unroll
    for (int nn = 0; nn < 2; nn++)
#pragma unroll
      for (int ks = 0; ks < 2; ks++) {
        int row = wn + 32 + nn * 16 + l16;
        bv1[nn * 2 + ks] = *(const short8*)(sm + bbase + row * 128 +
                                            ((ks * 64 + lg * 16) ^ ((row & 7) << 4)));
      }
    if (pf) {
      gl16(A + aoff[1] + koff, sm + nb + 8192 + t * 16);
      gl16(B + boff[1] + koff, sm + 65536 + nb + 8192 + t * 16);
    }
    __builtin_amdgcn_s_setprio(1);
    PHASE_MFMA(0, 1, bv1)
    __builtin_amdgcn_s_setprio(0);
    __builtin_amdgcn_s_barrier();

    // ---- phase 2: (mh1, nh1) ----
#pragma unroll
    for (int mi = 0; mi < 4; mi++)
#pragma unroll
      for (int ks = 0; ks < 2; ks++) {
        int row = wm + 64 + mi * 16 + l16;
        av[mi * 2 + ks] = *(const short8*)(sm + abase + row * 128 +
                                           ((ks * 64 + lg * 16) ^ ((row & 7) << 4)));
      }
    if (pf) {
      gl16(A + aoff[2] + koff, sm + nb + 16384 + t * 16);
      gl16(B + boff[2] + koff, sm + 65536 + nb + 16384 + t * 16);
    }
    __builtin_amdgcn_s_setprio(1);
    PHASE_MFMA(1, 1, bv1)
    __builtin_amdgcn_s_setprio(0);
    __builtin_amdgcn_s_barrier();

    // ---- phase 3: (mh1, nh0) ----
    if (pf) {
      gl16(A + aoff[3] + koff, sm + nb + 24576 + t * 16);
      gl16(B + boff[3] + koff, sm + 65536 + nb + 24576 + t * 16);
    }
    __builtin_amdgcn_s_setprio(1);
    PHASE_MFMA(1, 0, bv0)
    __builtin_amdgcn_s_setprio(0);
    asm volatile("s_waitcnt vmcnt(0)" ::: "memory");
    __builtin_amdgcn_s_barrier();
    __builtin_amdgcn_sched_barrier(0);
  }

  // epilogue
#pragma unroll
  for (int m = 0; m < 8; m++) {
    int row0 = bm * 256 + wm + m * 16 + lg * 4;
#pragma unroll
    for (int n = 0; n < 4; n++) {
      int col = bn * 256 + wn + n * 16 + l16;
      if (col < NC) {
#pragma unroll
        for (int rr = 0; rr < 4; rr++)
          store_out(C, (size_t)(row0 + rr) * NC + col, acc[m][n][rr]);
      }
    }
  }
}

// ---- conv(KW=4) + silu + q/k L2-norm, time-chunked (halo L1-reuse) ----
// grid 256 = (b, s-chunk of 16); 1024 threads, 8 ch/thread covering 8192 ch.
__global__ __launch_bounds__(1024)
void conv_silu_norm(const unsigned short* __restrict__ qkvz, const float* __restrict__ conv_w,
                    unsigned short* __restrict__ qkvs) {
  const int blk = blockIdx.x;
  const int b = blk >> 6;
  const int s0 = (blk & 63) << 4;
  const int t = threadIdx.x;
  const int c0 = t * 8;
  float w[8][4];
#pragma unroll
  for (int e = 0; e < 8; e++) {
    float4v wv = *(const float4v*)&conv_w[(c0 + e) * 4];
    w[e][0] = wv[0]; w[e][1] = wv[1]; w[e][2] = wv[2]; w[e][3] = wv[3];
  }
  const size_t base = (size_t)(b << 10) * NP + c0;
  const bool qk = c0 < 4096;
  const float qsc = (c0 < 2048) ? 0.08838834764831845f : 1.f;
#pragma unroll 1
  for (int i = 0; i < 16; i++) {
    const int s = s0 + i;
    float acc[8] = {0.f, 0.f, 0.f, 0.f, 0.f, 0.f, 0.f, 0.f};
#pragma unroll
    for (int j = 0; j < 4; j++) {
      const int sj = s - 3 + j;
      if (sj >= 0) {
        short8 v8 = *(const short8*)&qkvz[base + (size_t)sj * NP];
#pragma unroll
        for (int e = 0; e < 8; e++) acc[e] = fmaf(b2f((unsigned short)v8[e]), w[e][j], acc[e]);
      }
    }
    float out[8];
#pragma unroll
    for (int e = 0; e < 8; e++) { float xv = acc[e]; out[e] = xv * (1.f / (1.f + expf(-xv))); }
    if (qk) {
      float ss = 0.f;
#pragma unroll
      for (int e = 0; e < 8; e++) ss += out[e] * out[e];
      ss += __shfl_xor(ss, 1); ss += __shfl_xor(ss, 2);
      ss += __shfl_xor(ss, 4); ss += __shfl_xor(ss, 8);
      float sc = rsqrtf(ss + 1e-6f) * qsc;
#pragma unroll
      for (int e = 0; e < 8; e++) out[e] *= sc;
    }
    short8 o;
#pragma unroll
    for (int e = 0; e < 8; e++) o[e] = (short)f2b(out[e]);
    *(short8*)&qkvs[(size_t)((b << 10) + s) * 8192 + c0] = o;
  }
}

// ---- conv_state output: (B,CI,KW) fp32 from pre-conv qkv ----
__global__ void conv_state_k(const unsigned short* __restrict__ qkvz, float* __restrict__ cs) {
  int idx = blockIdx.x * 256 + threadIdx.x;  // < 131072 = 4*8192*4
  int b = idx >> 15;
  int rem = idx & 32767;
  int c = rem >> 2;
  int j = rem & 3;
  cs[idx] = b2f(qkvz[(size_t)(b * 1024 + 1020 + j) * NP + c]);
}

// ---- g / beta from a,b columns ----
__global__ void gb_kernel(const unsigned short* __restrict__ qkvz, const float* __restrict__ A_log,
                          const float* __restrict__ dt_bias, float* __restrict__ g,
                          float* __restrict__ bet) {
  int idx = blockIdx.x * 256 + threadIdx.x;  // < 4096*64
  int m = idx >> 6, n = idx & 63;
  if (n < 32) {
    float a = b2f(qkvz[(size_t)m * NP + 12288 + n]) + dt_bias[n];
    float sp = (a > 20.f) ? a : log1pf(expf(a));
    g[m * 32 + n] = -expf(A_log[n]) * sp;
  } else {
    int nn = n - 32;
    float bb = b2f(qkvz[(size_t)m * NP + 12320 + nn]);
    bet[m * 32 + nn] = 1.f / (1.f + expf(-bb));
  }
}

// ---- chunked delta-rule scan (UT transform), C=64, MFMA throughout ----
__global__ __launch_bounds__(256)
void scan_chunk(const unsigned short* __restrict__ qkvs, const float* __restrict__ g,
                const float* __restrict__ bet, unsigned short* __restrict__ y,
                float* __restrict__ state_out) {
  __shared__ __align__(16) unsigned short Kb[64][128];
  __shared__ __align__(16) unsigned short Qb[64][128];
  __shared__ __align__(16) unsigned short Sb[64][128];
  __shared__ __align__(16) unsigned short Ktt[128][64];
  __shared__ __align__(16) unsigned short Mb[64][64];
  __shared__ __align__(16) unsigned short Nb[64][64];
  __shared__ __align__(16) unsigned short Dbf[64][64];
  __shared__ __align__(16) unsigned short Vt[64][64];   // also reused as obuf
  __shared__ __align__(16) unsigned short Tb[4][16][16];
  __shared__ __align__(16) unsigned short rtmp[64][16];
  __shared__ float Gar[64];
  __shared__ float gamv[64];
  __shared__ float barr[64];
  __shared__ float gcs[2];

  const int bid = blockIdx.x;
  const int b = bid >> 6;
  const int h = (bid >> 1) & 31;
  const int half = bid & 1;
  const int hk = h >> 1;
  const int t = threadIdx.x;
  const int wv = t >> 6, lane = t & 63;
  const int l16 = lane & 15, lg = lane >> 4;
  const int bS = b << 10;

  float4v accS[8] = {};
  for (int idx = t; idx < 64 * 128; idx += 256) (&Sb[0][0])[idx] = 0;

  for (int ch = 0; ch < 16; ch++) {
    const int s0 = ch << 6;
    // ---- phase 1: stage Kb, Qb (swizzled via source permutation), Vt, g/beta ----
    {
#pragma unroll
      for (int rep = 0; rep < 4; rep++) {
        int rb = wv * 16 + rep * 4;
        int i = rb + (lane >> 4);
        int cg = (lane & 15) ^ (i & 7);
        const unsigned short* gk = qkvs + (size_t)(bS + s0 + i) * 8192 + 2048 + hk * 128 + cg * 8;
        gl16(gk, (char*)(&Kb[rb][0] + lane * 8));
        const unsigned short* gq = qkvs + (size_t)(bS + s0 + i) * 8192 + hk * 128 + cg * 8;
        gl16(gq, (char*)(&Qb[rb][0] + lane * 8));
      }
    }
    {
      int tt = t >> 2, q4 = t & 3;
      const unsigned short* gv = qkvs + (size_t)(bS + s0 + tt) * 8192 + 4096 + h * 128 + half * 64 + q4 * 16;
      short8 v0 = *(const short8*)gv;
      short8 v1 = *(const short8*)(gv + 8);
#pragma unroll
      for (int e = 0; e < 8; e++) {
        int v = q4 * 16 + e;
        Vt[v][tt ^ ((v & 7) << 3)] = (unsigned short)v0[e];
        v = q4 * 16 + 8 + e;
        Vt[v][tt ^ ((v & 7) << 3)] = (unsigned short)v1[e];
      }
    }
    if (t < 64) {
      float gt = g[(bS + s0 + t) * 32 + h];
      float bt = bet[(bS + s0 + t) * 32 + h];
#pragma unroll
      for (int d = 1; d < 64; d <<= 1) {
        float o = __shfl_up(gt, d);
        if (t >= d) gt += o;
      }
      Gar[t] = gt;
      gamv[t] = __expf(gt);
      barr[t] = bt;
      if (t == 63) { gcs[0] = gt; gcs[1] = __expf(gt); }
    }
    __syncthreads();

    // ---- phase 2: KK^T -> Mb, QK^T -> Nb; build Ktt ----
    {
      float4v aK[4] = {}, aQ[4] = {};
      const int arow = wv * 16 + l16;
      const int asw = (arow & 7) << 3;
#pragma unroll
      for (int kk = 0; kk < 4; kk++) {
        short8 av = *(const short8*)&Kb[arow][(kk * 32 + lg * 8) ^ asw];
        short8 aq = *(const short8*)&Qb[arow][(kk * 32 + lg * 8) ^ asw];
#pragma unroll
        for (int j = 0; j < 4; j++) {
          int brow = j * 16 + l16;
          short8 bv = *(const short8*)&Kb[brow][(kk * 32 + lg * 8) ^ ((brow & 7) << 3)];
          aK[j] = MFMA32(av, bv, aK[j]);
          aQ[j] = MFMA32(aq, bv, aQ[j]);
        }
      }
#pragma unroll
      for (int j = 0; j < 4; j++) {
#pragma unroll
        for (int reg = 0; reg < 4; reg++) {
          int tt = wv * 16 + lg * 4 + reg;
          int ii = j * 16 + l16;
          float sc = __expf(Gar[tt] - Gar[ii]);
          float mv = (ii < tt) ? aK[j][reg] * barr[tt] * sc : 0.f;
          float nv = (ii <= tt) ? aQ[j][reg] * sc : 0.f;
          Mb[tt][(ii ^ ((tt & 7) << 3))] = f2b(mv);
          Nb[tt][(ii ^ ((tt & 7) << 3))] = f2b(nv);
        }
      }
    }
    {
      int i = t >> 2, q4 = t & 3;
      float sc = __expf(gcs[0] - Gar[i]);
      int isw = (i & 7) << 3;
#pragma unroll
      for (int e8 = 0; e8 < 4; e8++) {
        int d0 = q4 * 32 + e8 * 8;
        short8 kv = *(const short8*)&Kb[i][d0 ^ isw];
#pragma unroll
        for (int e = 0; e < 8; e++) {
          int d = d0 + e;
          Ktt[d][i ^ ((d & 7) << 3)] = f2b(b2f((unsigned short)kv[e]) * sc);
        }
      }
    }
    __syncthreads();

    // ---- phase 3: P0t = S0 K^T; RHS -> Dbf; T-inverse -> Tb ----
    {
      float4v acc[4] = {};
      const int arow = wv * 16 + l16;  // v
      const int asw = (arow & 7) << 3;
#pragma unroll
      for (int kk = 0; kk < 4; kk++) {
        short8 av = *(const short8*)&Sb[arow][(kk * 32 + lg * 8) ^ asw];
#pragma unroll
        for (int j = 0; j < 4; j++) {
          int brow = j * 16 + l16;  // t
          short8 bv = *(const short8*)&Kb[brow][(kk * 32 + lg * 8) ^ ((brow & 7) << 3)];
          acc[j] = MFMA32(av, bv, acc[j]);
        }
      }
#pragma unroll
      for (int j = 0; j < 4; j++) {
#pragma unroll
        for (int reg = 0; reg < 4; reg++) {
          int v = wv * 16 + lg * 4 + reg;
          int tt = j * 16 + l16;
          float vtv = b2f(Vt[v][tt ^ ((v & 7) << 3)]);
          float val = barr[tt] * (vtv - gamv[tt] * acc[j][reg]);
          Dbf[v][tt ^ ((v & 7) << 3)] = f2b(val);
        }
      }
    }
    {
      // T-inverse of diagonal block wv (unit lower)
      float Lrow[16];
#pragma unroll
      for (int i = 0; i < 16; i++)
        Lrow[i] = b2f(Mb[wv * 16 + l16][((wv * 16 + i) ^ ((l16 & 7) << 3))]);
      float Tc[16];
#pragma unroll
      for (int i = 0; i < 16; i++) Tc[i] = (i == l16) ? 1.f : 0.f;
#pragma unroll
      for (int tt = 1; tt < 16; tt++) {
        float s = 0.f;
#pragma unroll
        for (int i = 0; i < 16; i++) {
          if (i < tt)
            s += __int_as_float(__builtin_amdgcn_readlane(__float_as_int(Lrow[i]), tt)) * Tc[i];
        }
        Tc[tt] = ((tt == l16) ? 1.f : 0.f) - s;
      }
      if (lane < 16) {
#pragma unroll
        for (int tt = 0; tt < 16; tt++) Tb[wv][tt][l16] = f2b(Tc[tt]);
      }
    }
    __syncthreads();

    // ---- phase 4: block forward substitution, D = (I+M)^{-1} RHS ----
    {
      short8 a = (short8)(short)0, bT = (short8)(short)0;
      const int arow = wv * 16 + l16;
      if (lg < 2) {
        a = *(const short8*)&Dbf[arow][((lg * 8) ^ ((arow & 7) << 3))];
        bT = *(const short8*)&Tb[0][l16][lg * 8];
      }
      float4v acc0 = {};
      acc0 = MFMA32(a, bT, acc0);
      __syncthreads();
#pragma unroll
      for (int reg = 0; reg < 4; reg++) {
        int v = wv * 16 + lg * 4 + reg;
        Dbf[v][(l16 ^ ((v & 7) << 3))] = f2b(acc0[reg]);
      }
    }
    __syncthreads();
#pragma unroll
    for (int s = 1; s < 4; s++) {
      float4v acc = {};
      const int arow = wv * 16 + l16;
      const int mrow = s * 16 + l16;
#pragma unroll
      for (int j = 0; j < 3; j++) {
        if (j < s) {
          short8 a = (short8)(short)0, bM = (short8)(short)0;
          if (lg < 2) {
            a  = *(const short8*)&Dbf[arow][((j * 16 + lg * 8) ^ ((arow & 7) << 3))];
            bM = *(const short8*)&Mb[mrow][((j * 16 + lg * 8) ^ ((mrow & 7) << 3))];
          }
          acc = MFMA32(a, bM, acc);
        }
      }
#pragma unroll
      for (int reg = 0; reg < 4; reg++) {
        int v = wv * 16 + lg * 4 + reg;
        float rt = b2f(Dbf[v][((s * 16 + l16) ^ ((v & 7) << 3))]);
        rtmp[v][l16] = f2b(rt - acc[reg]);
      }
      __syncthreads();
      short8 a2 = (short8)(short)0, bT = (short8)(short)0;
      if (lg < 2) {
        a2 = *(const short8*)&rtmp[wv * 16 + l16][lg * 8];
        bT = *(const short8*)&Tb[s][l16][lg * 8];
      }
      float4v acc2 = {};
      acc2 = MFMA32(a2, bT, acc2);
      __syncthreads();
#pragma unroll
      for (int reg = 0; reg < 4; reg++) {
        int v = wv * 16 + lg * 4 + reg;
        Dbf[v][((s * 16 + l16) ^ ((v & 7) << 3))] = f2b(acc2[reg]);
      }
      __syncthreads();
    }

    // ---- phase 5: O = diag(gam) Q S0^T + N D ----
    {
      float4v acc[4] = {};
      const int arow = wv * 16 + l16;  // t
      const int asw = (arow & 7) << 3;
#pragma unroll
      for (int kk = 0; kk < 4; kk++) {
        short8 aq = *(const short8*)&Qb[arow][(kk * 32 + lg * 8) ^ asw];
#pragma unroll
        for (int j = 0; j < 4; j++) {
          int brow = j * 16 + l16;  // v
          short8 bs = *(const short8*)&Sb[brow][(kk * 32 + lg * 8) ^ ((brow & 7) << 3)];
          acc[j] = MFMA32(aq, bs, acc[j]);
        }
      }
#pragma unroll
      for (int j = 0; j < 4; j++) {
#pragma unroll
        for (int reg = 0; reg < 4; reg++) {
          int tt = wv * 16 + lg * 4 + reg;
          acc[j][reg] *= gamv[tt];
        }
      }
#pragma unroll
      for (int kk = 0; kk < 2; kk++) {
        short8 an = *(const short8*)&Nb[arow][(kk * 32 + lg * 8) ^ asw];
#pragma unroll
        for (int j = 0; j < 4; j++) {
          int brow = j * 16 + l16;  // v
          short8 bd = *(const short8*)&Dbf[brow][(kk * 32 + lg * 8) ^ ((brow & 7) << 3)];
          acc[j] = MFMA32(an, bd, acc[j]);
        }
      }
      __syncthreads();  // Vt consumed; reuse as obuf
#pragma unroll
      for (int j = 0; j < 4; j++) {
#pragma unroll
        for (int reg = 0; reg < 4; reg++) {
          int tt = wv * 16 + lg * 4 + reg;
          int v = j * 16 + l16;
          Vt[tt][v ^ ((tt & 7) << 3)] = f2b(acc[j][reg]);
        }
      }
    }
    __syncthreads();
    {
      int tt = t >> 2, q4 = t & 3;
      int sw = (tt & 7) << 3;
      unsigned short* yg = y + (size_t)(bS + s0 + tt) * 4096 + h * 128 + half * 64 + q4 * 16;
      short8 o0 = *(const short8*)&Vt[tt][(q4 * 16) ^ sw];
      short8 o1 = *(const short8*)&Vt[tt][(q4 * 16 + 8) ^ sw];
      *(short8*)yg = o0;
      *(short8*)(yg + 8) = o1;
    }

    // ---- phase 6: state update S = gamC * S + D^T Ktt ----
    {
      float gC = gcs[1];
#pragma unroll
      for (int dt = 0; dt < 8; dt++)
#pragma unroll
        for (int reg = 0; reg < 4; reg++) accS[dt][reg] *= gC;
      const int arow = wv * 16 + l16;  // v
      const int asw = (arow & 7) << 3;
#pragma unroll
      for (int kk = 0; kk < 2; kk++) {
        short8 ad = *(const short8*)&Dbf[arow][(kk * 32 + lg * 8) ^ asw];
#pragma unroll
        for (int dt = 0; dt < 8; dt++) {
          int brow = dt * 16 + l16;  // d
          short8 bk = *(const short8*)&Ktt[brow][(kk * 32 + lg * 8) ^ ((brow & 7) << 3)];
          accS[dt] = MFMA32(ad, bk, accS[dt]);
        }
      }
      __syncthreads();
#pragma unroll
      for (int dt = 0; dt < 8; dt++) {
#pragma unroll
        for (int reg = 0; reg < 4; reg++) {
          int v = wv * 16 + lg * 4 + reg;
          int d = dt * 16 + l16;
          Sb[v][d ^ ((v & 7) << 3)] = f2b(accS[dt][reg]);
        }
      }
    }
    __syncthreads();
  }

  // final state writeout (fp32)
#pragma unroll
  for (int dt = 0; dt < 8; dt++) {
#pragma unroll
    for (int reg = 0; reg < 4; reg++) {
      int v = wv * 16 + lg * 4 + reg;
      int d = dt * 16 + l16;
      state_out[((size_t)((b * 32 + h) * 128 + half * 64 + v)) * 128 + d] = accS[dt][reg];
    }
  }
}

// ---- RMSNorm over DV * norm_w * silu(z) -> yn bf16 ----
__global__ __launch_bounds__(256)
void rms_silu(const unsigned short* __restrict__ y, const unsigned short* __restrict__ qkvz,
              const float* __restrict__ nw, unsigned short* __restrict__ yn) {
  int m = blockIdx.x;
  int t = threadIdx.x;
  int head = t >> 3, oct = t & 7;
  int vb = head * 128 + oct * 16;
  const unsigned short* yp = y + (size_t)m * 4096 + vb;
  float yy[16];
  short8 y0 = *(const short8*)yp, y1 = *(const short8*)(yp + 8);
#pragma unroll
  for (int e = 0; e < 8; e++) { yy[e] = b2f((unsigned short)y0[e]); yy[8 + e] = b2f((unsigned short)y1[e]); }
  float ss = 0.f;
#pragma unroll
  for (int e = 0; e < 16; e++) ss += yy[e] * yy[e];
  ss += __shfl_xor(ss, 1); ss += __shfl_xor(ss, 2); ss += __shfl_xor(ss, 4);
  float rinv = rsqrtf(ss * (1.f / 128.f) + 1e-6f);
  const unsigned short* zp = qkvz + (size_t)m * NP + 8192 + vb;
  short8 z0 = *(const short8*)zp, z1 = *(const short8*)(zp + 8);
  short8 o0, o1;
#pragma unroll
  for (int e = 0; e < 8; e++) {
    float z = b2f((unsigned short)z0[e]);
    float v = nw[oct * 16 + e] * yy[e] * rinv * (z / (1.f + expf(-z)));
    o0[e] = (short)f2b(v);
    z = b2f((unsigned short)z1[e]);
    v = nw[oct * 16 + 8 + e] * yy[8 + e] * rinv * (z / (1.f + expf(-z)));
    o1[e] = (short)f2b(v);
  }
  unsigned short* op = yn + (size_t)m * 4096 + vb;
  *(short8*)op = o0;
  *(short8*)(op + 8) = o1;
}

extern "C" void kernel_launch(void* const* d_in, const int* in_sizes, int n_in,
                              void* d_out, int out_size, void* d_ws, size_t ws_size,
                              hipStream_t stream) {
  if (ws_size < WS_NEED) return;  // guard: fail with clean absmax, not a fault

  const float* x     = (const float*)d_in[0];
  const float* Wqkv  = (const float*)d_in[1];
  const float* Wz    = (const float*)d_in[2];
  const float* Wa    = (const float*)d_in[3];
  const float* Wb    = (const float*)d_in[4];
  const float* convw = (const float*)d_in[5];
  const float* Alog  = (const float*)d_in[6];
  const float* dtb   = (const float*)d_in[7];
  const float* nw    = (const float*)d_in[8];
  const float* Wout  = (const float*)d_in[9];

  char* ws = (char*)d_ws;
  unsigned short* qkvz = (unsigned short*)(ws + OFF_QKVZ);
  unsigned short* xb   = (unsigned short*)(ws + OFF_XB);
  unsigned short* wcat = (unsigned short*)(ws + OFF_WCAT);
  unsigned short* qkvs = (unsigned short*)(ws + OFF_QKVS);
  unsigned short* ynb  = (unsigned short*)(ws + OFF_YN);
  unsigned short* wob  = (unsigned short*)(ws + OFF_WOB);
  float* gbuf          = (float*)(ws + OFF_G);
  float* bbuf          = (float*)(ws + OFF_BET);

  float* outp       = (float*)d_out;
  float* conv_state = outp + 8388608;             // B*S*H
  float* state      = outp + 8388608 + 131072;    // + B*CI*KW
  unsigned short* ybuf = (unsigned short*)d_out;  // y bf16 scratch over outp region

  castk<<<8192, 256, 0, stream>>>(x, xb, 2097152);
  prep_wcat<<<25088, 256, 0, stream>>>(Wqkv, Wz, Wa, Wb, wcat);

  gemm256<unsigned short><<<784, 512, 0, stream>>>(xb, wcat, qkvz, 2048, 49, NP);

  conv_silu_norm<<<256, 1024, 0, stream>>>(qkvz, convw, qkvs);
  conv_state_k<<<512, 256, 0, stream>>>(qkvz, conv_state);
  gb_kernel<<<1024, 256, 0, stream>>>(qkvz, Alog, dtb, gbuf, bbuf);

  scan_chunk<<<256, 256, 0, stream>>>(qkvs, gbuf, bbuf, ybuf, state);

  rms_silu<<<4096, 256, 0, stream>>>(ybuf, qkvz, nw, ynb);
  castk<<<8192, 256, 0, stream>>>(Wout, wob, 2097152);

  gemm256<float><<<128, 512, 0, stream>>>(ynb, wob, outp, 4096, 8, 2048);
}

// Round 7
// 568.178 us; speedup vs baseline: 2.0446x; 1.0591x over previous
//
#include <hip/hip_runtime.h>
#include <cstdint>
#include <cstddef>

typedef __attribute__((ext_vector_type(8))) short short8;
typedef __attribute__((ext_vector_type(4))) short short4v;
typedef __attribute__((ext_vector_type(4))) float float4v;

#define DEV static __device__ __forceinline__

DEV float b2f(unsigned short u) { return __uint_as_float(((unsigned int)u) << 16); }
DEV unsigned short f2b(float f) {
  unsigned int u = __float_as_uint(f);
  u = (u + 0x7fffu + ((u >> 16) & 1u)) >> 16;
  return (unsigned short)u;
}

#define MFMA32(a, b, c) __builtin_amdgcn_mfma_f32_16x16x32_bf16(a, b, c, 0, 0, 0)

// ---- problem sizes ----
static constexpr int NP   = 12416;  // qkvz stride: 8192 qkv + 4096 z + 32 a + 32 b + 64 pad
static constexpr int NPAD = 12544;  // wcat rows padded to 49*256 for 256-tile GEMM

// ---- ws layout (bytes), lifetime-overlaid; peak ~162 MB ----
static constexpr size_t OFF_QKVZ = 0;
static constexpr size_t SZ_QKVZ  = (size_t)4096*NP*2;        // 101,711,872
static constexpr size_t OFF_XB   = SZ_QKVZ;
static constexpr size_t SZ_XB    = (size_t)4096*2048*2;      // 16,777,216
static constexpr size_t OFF_WCAT = OFF_XB + SZ_XB;
static constexpr size_t SZ_WCAT  = (size_t)NPAD*2048*2;      // 51,380,224
static constexpr size_t OFF_QKVS = OFF_XB;                   // overlays xb+wcat after GEMM1
static constexpr size_t SZ_QKVS  = (size_t)4096*8192*2;      // 67,108,864
static constexpr size_t OFF_G    = OFF_XB + SZ_QKVS;         // fits in gap before wcat end
static constexpr size_t OFF_BET  = OFF_G + (size_t)4096*32*4;
static constexpr size_t OFF_YN   = OFF_XB;                   // after scan
static constexpr size_t SZ_YN    = (size_t)4096*4096*2;
static constexpr size_t OFF_WOB  = OFF_YN + SZ_YN;
static constexpr size_t WS_NEED  = OFF_WCAT + SZ_WCAT;       // 169,869,312

// ---- helpers ----
DEV void gl16(const unsigned short* g, char* l) {
  __builtin_amdgcn_global_load_lds((const __attribute__((address_space(1))) unsigned int*)g,
                                   (__attribute__((address_space(3))) unsigned int*)l,
                                   16, 0, 0);
}

DEV void store_out(unsigned short* C, size_t off, float v) { C[off] = f2b(v); }
DEV void store_out(float* C, size_t off, float v)          { C[off] = v; }

// ---- generic cast fp32 -> bf16 (n multiple of 4) ----
__global__ void castk(const float* __restrict__ in, unsigned short* __restrict__ out, int n4) {
  int idx = blockIdx.x * 256 + threadIdx.x;
  if (idx >= n4) return;
  float4v v = ((const float4v*)in)[idx];
  short4v o;
  o[0] = (short)f2b(v[0]); o[1] = (short)f2b(v[1]);
  o[2] = (short)f2b(v[2]); o[3] = (short)f2b(v[3]);
  ((short4v*)out)[idx] = o;
}

// ---- build concatenated weight [12544][2048] bf16 ----
__global__ void prep_wcat(const float* __restrict__ Wqkv, const float* __restrict__ Wz,
                          const float* __restrict__ Wa, const float* __restrict__ Wb,
                          unsigned short* __restrict__ Wcat) {
  size_t e4 = (size_t)blockIdx.x * 256 + threadIdx.x;
  if (e4 >= (size_t)NPAD * 2048 / 4) return;
  size_t e = e4 * 4;
  int row = (int)(e >> 11);
  int col = (int)(e & 2047);
  float4v v;
  if (row < 8192)       v = *(const float4v*)&Wqkv[(size_t)row * 2048 + col];
  else if (row < 12288) v = *(const float4v*)&Wz[(size_t)(row - 8192) * 2048 + col];
  else if (row < 12320) v = *(const float4v*)&Wa[(size_t)(row - 12288) * 2048 + col];
  else if (row < 12352) v = *(const float4v*)&Wb[(size_t)(row - 12320) * 2048 + col];
  else                  v = (float4v){0.f, 0.f, 0.f, 0.f};
  short4v o;
  o[0] = (short)f2b(v[0]); o[1] = (short)f2b(v[1]);
  o[2] = (short)f2b(v[2]); o[3] = (short)f2b(v[3]);
  *(short4v*)&Wcat[e] = o;
}

// ========== BM x 256 phase-interleaved bf16 MFMA GEMM (BM = 256 or 128) =====
// C[M][NC] = A[M][K] @ B[N][K]^T. 512 thr = 8 waves (2M x 4N), BK=64.
// All next-K-tile global_load_lds issued at phase 0 (~3 phases of MFMA cover
// before the single vmcnt(0) drain at the last phase). XOR-swizzled LDS via
// pre-swizzled global source. XCD-aware bijective block swizzle; tile order
// bn-major (GEMM1: B streamed once per XCD-col-slab) or bm-major (GEMM2).
#define PHASE_MFMA(mh, nh, bvv)                                              \
  _Pragma("unroll") for (int mi = 0; mi < 4; mi++)                           \
  _Pragma("unroll") for (int nn = 0; nn < 2; nn++)                           \
  _Pragma("unroll") for (int ks = 0; ks < 2; ks++)                           \
    acc[(mh)*4 + mi][(nh)*2 + nn] =                                          \
        MFMA32(av[mi*2 + ks], bvv[nn*2 + ks], acc[(mh)*4 + mi][(nh)*2 + nn]);

template <int BM, bool BNMAJOR, typename OutT>
__global__ __launch_bounds__(512, 2)
void gemm2x(const unsigned short* __restrict__ A, const unsigned short* __restrict__ B,
            OutT* __restrict__ C, int K, int nbm, int nbn, int NC) {
  constexpr int MH = BM / 128;       // 2 or 1 M-halves (phases = MH*2)
  constexpr int ALOADS = BM / 64;    // gl16 rounds for one A K-tile
  constexpr int ABUF = BM * 128;     // bytes per A K-tile buffer
  __shared__ __align__(16) char sm[2 * ABUF + 65536];
  const int t = threadIdx.x;
  const int cpx = gridDim.x >> 3;
  int wg = blockIdx.x;
  wg = (wg & 7) * cpx + (wg >> 3);   // bijective XCD swizzle (grid % 8 == 0)
  const int bm = BNMAJOR ? (wg % nbm) : (wg / nbn);
  const int bn = BNMAJOR ? (wg / nbm) : (wg % nbn);

  const int wv = t >> 6, lane = t & 63;
  const int l16 = lane & 15, lg = lane >> 4;
  const int wm = (wv >> 2) * (BM / 2);
  const int wn = (wv & 3) * 64;

  size_t aoff[ALOADS], boff[4];
#pragma unroll
  for (int r = 0; r < ALOADS; r++) {
    int L = r * 8192 + t * 16;
    int row = L >> 7;
    int col = ((L & 127) ^ ((row & 7) << 4)) >> 1;
    aoff[r] = (size_t)(bm * BM + row) * K + col;
  }
#pragma unroll
  for (int r = 0; r < 4; r++) {
    int L = r * 8192 + t * 16;
    int row = L >> 7;
    int col = ((L & 127) ^ ((row & 7) << 4)) >> 1;
    boff[r] = (size_t)(bn * 256 + row) * K + col;
  }

  float4v acc[MH * 4][4] = {};
  const int NKT = K >> 6;

  // prologue: stage K-tile 0 into buf 0
#pragma unroll
  for (int r = 0; r < ALOADS; r++) gl16(A + aoff[r], sm + r * 8192 + t * 16);
#pragma unroll
  for (int r = 0; r < 4; r++) gl16(B + boff[r], sm + 2 * ABUF + r * 8192 + t * 16);
  asm volatile("s_waitcnt vmcnt(0)" ::: "memory");
  __builtin_amdgcn_s_barrier();

  for (int kt = 0; kt < NKT; kt++) {
    const int cur = kt & 1;
    char* ab  = sm + cur * ABUF;
    char* bb  = sm + 2 * ABUF + cur * 32768;
    char* anb = sm + (cur ^ 1) * ABUF;
    char* bnb = sm + 2 * ABUF + (cur ^ 1) * 32768;
    const bool pf = (kt + 1 < NKT);
    const size_t koff = (size_t)(kt + 1) * 64;
    short8 av[8], bv0[4], bv1[4];

    // ---- phase 0: read A(mh0)+B(nh0); issue ALL next-tile loads ----
#pragma unroll
    for (int mi = 0; mi < 4; mi++)
#pragma unroll
      for (int ks = 0; ks < 2; ks++) {
        int row = wm + mi * 16 + l16;
        av[mi * 2 + ks] = *(const short8*)(ab + row * 128 +
                                           ((ks * 64 + lg * 16) ^ ((row & 7) << 4)));
      }
#pragma unroll
    for (int nn = 0; nn < 2; nn++)
#pragma unroll
      for (int ks = 0; ks < 2; ks++) {
        int row = wn + nn * 16 + l16;
        bv0[nn * 2 + ks] = *(const short8*)(bb + row * 128 +
                                            ((ks * 64 + lg * 16) ^ ((row & 7) << 4)));
      }
    if (pf) {
#pragma unroll
      for (int r = 0; r < ALOADS; r++) gl16(A + aoff[r] + koff, anb + r * 8192 + t * 16);
#pragma unroll
      for (int r = 0; r < 4; r++) gl16(B + boff[r] + koff, bnb + r * 8192 + t * 16);
    }
    __builtin_amdgcn_s_setprio(1);
    PHASE_MFMA(0, 0, bv0)
    __builtin_amdgcn_s_setprio(0);
    __builtin_amdgcn_s_barrier();

    // ---- phase 1: read B(nh1); MFMA (0,1) ----
#pragma unroll
    for (int nn = 0; nn < 2; nn++)
#pragma unroll
      for (int ks = 0; ks < 2; ks++) {
        int row = wn + 32 + nn * 16 + l16;
        bv1[nn * 2 + ks] = *(const short8*)(bb + row * 128 +
                                            ((ks * 64 + lg * 16) ^ ((row & 7) << 4)));
      }
    __builtin_amdgcn_s_setprio(1);
    PHASE_MFMA(0, 1, bv1)
    __builtin_amdgcn_s_setprio(0);
    if constexpr (MH == 1) {
      asm volatile("s_waitcnt vmcnt(0)" ::: "memory");
      __builtin_amdgcn_s_barrier();
      __builtin_amdgcn_sched_barrier(0);
    } else {
      __builtin_amdgcn_s_barrier();

      // ---- phase 2: read A(mh1); MFMA (1,1) ----
#pragma unroll
      for (int mi = 0; mi < 4; mi++)
#pragma unroll
        for (int ks = 0; ks < 2; ks++) {
          int row = wm + 64 + mi * 16 + l16;
          av[mi * 2 + ks] = *(const short8*)(ab + row * 128 +
                                             ((ks * 64 + lg * 16) ^ ((row & 7) << 4)));
        }
      __builtin_amdgcn_s_setprio(1);
      PHASE_MFMA(1, 1, bv1)
      __builtin_amdgcn_s_setprio(0);
      __builtin_amdgcn_s_barrier();

      // ---- phase 3: MFMA (1,0); drain ----
      __builtin_amdgcn_s_setprio(1);
      PHASE_MFMA(1, 0, bv0)
      __builtin_amdgcn_s_setprio(0);
      asm volatile("s_waitcnt vmcnt(0)" ::: "memory");
      __builtin_amdgcn_s_barrier();
      __builtin_amdgcn_sched_barrier(0);
    }
  }

  // epilogue
#pragma unroll
  for (int m = 0; m < MH * 4; m++) {
    int row0 = bm * BM + wm + m * 16 + lg * 4;
#pragma unroll
    for (int n = 0; n < 4; n++) {
      int col = bn * 256 + wn + n * 16 + l16;
      if (col < NC) {
#pragma unroll
        for (int rr = 0; rr < 4; rr++)
          store_out(C, (size_t)(row0 + rr) * NC + col, acc[m][n][rr]);
      }
    }
  }
}

// ---- conv(KW=4) + silu + q/k L2-norm, time-chunked (halo L1-reuse) ----
__global__ __launch_bounds__(1024)
void conv_silu_norm(const unsigned short* __restrict__ qkvz, const float* __restrict__ conv_w,
                    unsigned short* __restrict__ qkvs) {
  const int blk = blockIdx.x;
  const int b = blk >> 6;
  const int s0 = (blk & 63) << 4;
  const int t = threadIdx.x;
  const int c0 = t * 8;
  float w[8][4];
#pragma unroll
  for (int e = 0; e < 8; e++) {
    float4v wv = *(const float4v*)&conv_w[(c0 + e) * 4];
    w[e][0] = wv[0]; w[e][1] = wv[1]; w[e][2] = wv[2]; w[e][3] = wv[3];
  }
  const size_t base = (size_t)(b << 10) * NP + c0;
  const bool qk = c0 < 4096;
  const float qsc = (c0 < 2048) ? 0.08838834764831845f : 1.f;
#pragma unroll 1
  for (int i = 0; i < 16; i++) {
    const int s = s0 + i;
    float acc[8] = {0.f, 0.f, 0.f, 0.f, 0.f, 0.f, 0.f, 0.f};
#pragma unroll
    for (int j = 0; j < 4; j++) {
      const int sj = s - 3 + j;
      if (sj >= 0) {
        short8 v8 = *(const short8*)&qkvz[base + (size_t)sj * NP];
#pragma unroll
        for (int e = 0; e < 8; e++) acc[e] = fmaf(b2f((unsigned short)v8[e]), w[e][j], acc[e]);
      }
    }
    float out[8];
#pragma unroll
    for (int e = 0; e < 8; e++) { float xv = acc[e]; out[e] = xv * (1.f / (1.f + expf(-xv))); }
    if (qk) {
      float ss = 0.f;
#pragma unroll
      for (int e = 0; e < 8; e++) ss += out[e] * out[e];
      ss += __shfl_xor(ss, 1); ss += __shfl_xor(ss, 2);
      ss += __shfl_xor(ss, 4); ss += __shfl_xor(ss, 8);
      float sc = rsqrtf(ss + 1e-6f) * qsc;
#pragma unroll
      for (int e = 0; e < 8; e++) out[e] *= sc;
    }
    short8 o;
#pragma unroll
    for (int e = 0; e < 8; e++) o[e] = (short)f2b(out[e]);
    *(short8*)&qkvs[(size_t)((b << 10) + s) * 8192 + c0] = o;
  }
}

// ---- conv_state output: (B,CI,KW) fp32 from pre-conv qkv ----
__global__ void conv_state_k(const unsigned short* __restrict__ qkvz, float* __restrict__ cs) {
  int idx = blockIdx.x * 256 + threadIdx.x;  // < 131072 = 4*8192*4
  int b = idx >> 15;
  int rem = idx & 32767;
  int c = rem >> 2;
  int j = rem & 3;
  cs[idx] = b2f(qkvz[(size_t)(b * 1024 + 1020 + j) * NP + c]);
}

// ---- g / beta from a,b columns ----
__global__ void gb_kernel(const unsigned short* __restrict__ qkvz, const float* __restrict__ A_log,
                          const float* __restrict__ dt_bias, float* __restrict__ g,
                          float* __restrict__ bet) {
  int idx = blockIdx.x * 256 + threadIdx.x;  // < 4096*64
  int m = idx >> 6, n = idx & 63;
  if (n < 32) {
    float a = b2f(qkvz[(size_t)m * NP + 12288 + n]) + dt_bias[n];
    float sp = (a > 20.f) ? a : log1pf(expf(a));
    g[m * 32 + n] = -expf(A_log[n]) * sp;
  } else {
    int nn = n - 32;
    float bb = b2f(qkvz[(size_t)m * NP + 12320 + nn]);
    bet[m * 32 + nn] = 1.f / (1.f + expf(-bb));
  }
}

// ---- chunked delta-rule scan (UT transform), C=64, MFMA throughout ----
__global__ __launch_bounds__(256)
void scan_chunk(const unsigned short* __restrict__ qkvs, const float* __restrict__ g,
                const float* __restrict__ bet, unsigned short* __restrict__ y,
                float* __restrict__ state_out) {
  __shared__ __align__(16) unsigned short Kb[64][128];
  __shared__ __align__(16) unsigned short Qb[64][128];
  __shared__ __align__(16) unsigned short Sb[64][128];
  __shared__ __align__(16) unsigned short Ktt[128][64];
  __shared__ __align__(16) unsigned short Mb[64][64];
  __shared__ __align__(16) unsigned short Nb[64][64];
  __shared__ __align__(16) unsigned short Dbf[64][64];
  __shared__ __align__(16) unsigned short Vt[64][64];   // also reused as obuf
  __shared__ __align__(16) unsigned short Tb[4][16][16];
  __shared__ __align__(16) unsigned short rtmp[64][16];
  __shared__ float Gar[64];
  __shared__ float gamv[64];
  __shared__ float barr[64];
  __shared__ float gcs[2];

  const int bid = blockIdx.x;
  const int b = bid >> 6;
  const int h = (bid >> 1) & 31;
  const int half = bid & 1;
  const int hk = h >> 1;
  const int t = threadIdx.x;
  const int wv = t >> 6, lane = t & 63;
  const int l16 = lane & 15, lg = lane >> 4;
  const int bS = b << 10;

  float4v accS[8] = {};
  for (int idx = t; idx < 64 * 128; idx += 256) (&Sb[0][0])[idx] = 0;

  for (int ch = 0; ch < 16; ch++) {
    const int s0 = ch << 6;
    // ---- phase 1: stage Kb, Qb (swizzled via source permutation), Vt, g/beta ----
    {
#pragma unroll
      for (int rep = 0; rep < 4; rep++) {
        int rb = wv * 16 + rep * 4;
        int i = rb + (lane >> 4);
        int cg = (lane & 15) ^ (i & 7);
        const unsigned short* gk = qkvs + (size_t)(bS + s0 + i) * 8192 + 2048 + hk * 128 + cg * 8;
        gl16(gk, (char*)(&Kb[rb][0] + lane * 8));
        const unsigned short* gq = qkvs + (size_t)(bS + s0 + i) * 8192 + hk * 128 + cg * 8;
        gl16(gq, (char*)(&Qb[rb][0] + lane * 8));
      }
    }
    {
      int tt = t >> 2, q4 = t & 3;
      const unsigned short* gv = qkvs + (size_t)(bS + s0 + tt) * 8192 + 4096 + h * 128 + half * 64 + q4 * 16;
      short8 v0 = *(const short8*)gv;
      short8 v1 = *(const short8*)(gv + 8);
#pragma unroll
      for (int e = 0; e < 8; e++) {
        int v = q4 * 16 + e;
        Vt[v][tt ^ ((v & 7) << 3)] = (unsigned short)v0[e];
        v = q4 * 16 + 8 + e;
        Vt[v][tt ^ ((v & 7) << 3)] = (unsigned short)v1[e];
      }
    }
    if (t < 64) {
      float gt = g[(bS + s0 + t) * 32 + h];
      float bt = bet[(bS + s0 + t) * 32 + h];
#pragma unroll
      for (int d = 1; d < 64; d <<= 1) {
        float o = __shfl_up(gt, d);
        if (t >= d) gt += o;
      }
      Gar[t] = gt;
      gamv[t] = __expf(gt);
      barr[t] = bt;
      if (t == 63) { gcs[0] = gt; gcs[1] = __expf(gt); }
    }
    __syncthreads();

    // ---- phase 2: KK^T -> Mb, QK^T -> Nb; build Ktt ----
    {
      float4v aK[4] = {}, aQ[4] = {};
      const int arow = wv * 16 + l16;
      const int asw = (arow & 7) << 3;
#pragma unroll
      for (int kk = 0; kk < 4; kk++) {
        short8 av = *(const short8*)&Kb[arow][(kk * 32 + lg * 8) ^ asw];
        short8 aq = *(const short8*)&Qb[arow][(kk * 32 + lg * 8) ^ asw];
#pragma unroll
        for (int j = 0; j < 4; j++) {
          int brow = j * 16 + l16;
          short8 bv = *(const short8*)&Kb[brow][(kk * 32 + lg * 8) ^ ((brow & 7) << 3)];
          aK[j] = MFMA32(av, bv, aK[j]);
          aQ[j] = MFMA32(aq, bv, aQ[j]);
        }
      }
#pragma unroll
      for (int j = 0; j < 4; j++) {
#pragma unroll
        for (int reg = 0; reg < 4; reg++) {
          int tt = wv * 16 + lg * 4 + reg;
          int ii = j * 16 + l16;
          float sc = __expf(Gar[tt] - Gar[ii]);
          float mv = (ii < tt) ? aK[j][reg] * barr[tt] * sc : 0.f;
          float nv = (ii <= tt) ? aQ[j][reg] * sc : 0.f;
          Mb[tt][(ii ^ ((tt & 7) << 3))] = f2b(mv);
          Nb[tt][(ii ^ ((tt & 7) << 3))] = f2b(nv);
        }
      }
    }
    {
      int i = t >> 2, q4 = t & 3;
      float sc = __expf(gcs[0] - Gar[i]);
      int isw = (i & 7) << 3;
#pragma unroll
      for (int e8 = 0; e8 < 4; e8++) {
        int d0 = q4 * 32 + e8 * 8;
        short8 kv = *(const short8*)&Kb[i][d0 ^ isw];
#pragma unroll
        for (int e = 0; e < 8; e++) {
          int d = d0 + e;
          Ktt[d][i ^ ((d & 7) << 3)] = f2b(b2f((unsigned short)kv[e]) * sc);
        }
      }
    }
    __syncthreads();

    // ---- phase 3: P0t = S0 K^T; RHS -> Dbf; T-inverse -> Tb ----
    {
      float4v acc[4] = {};
      const int arow = wv * 16 + l16;  // v
      const int asw = (arow & 7) << 3;
#pragma unroll
      for (int kk = 0; kk < 4; kk++) {
        short8 av = *(const short8*)&Sb[arow][(kk * 32 + lg * 8) ^ asw];
#pragma unroll
        for (int j = 0; j < 4; j++) {
          int brow = j * 16 + l16;  // t
          short8 bv = *(const short8*)&Kb[brow][(kk * 32 + lg * 8) ^ ((brow & 7) << 3)];
          acc[j] = MFMA32(av, bv, acc[j]);
        }
      }
#pragma unroll
      for (int j = 0; j < 4; j++) {
#pragma unroll
        for (int reg = 0; reg < 4; reg++) {
          int v = wv * 16 + lg * 4 + reg;
          int tt = j * 16 + l16;
          float vtv = b2f(Vt[v][tt ^ ((v & 7) << 3)]);
          float val = barr[tt] * (vtv - gamv[tt] * acc[j][reg]);
          Dbf[v][tt ^ ((v & 7) << 3)] = f2b(val);
        }
      }
    }
    {
      // T-inverse of diagonal block wv (unit lower)
      float Lrow[16];
#pragma unroll
      for (int i = 0; i < 16; i++)
        Lrow[i] = b2f(Mb[wv * 16 + l16][((wv * 16 + i) ^ ((l16 & 7) << 3))]);
      float Tc[16];
#pragma unroll
      for (int i = 0; i < 16; i++) Tc[i] = (i == l16) ? 1.f : 0.f;
#pragma unroll
      for (int tt = 1; tt < 16; tt++) {
        float s = 0.f;
#pragma unroll
        for (int i = 0; i < 16; i++) {
          if (i < tt)
            s += __int_as_float(__builtin_amdgcn_readlane(__float_as_int(Lrow[i]), tt)) * Tc[i];
        }
        Tc[tt] = ((tt == l16) ? 1.f : 0.f) - s;
      }
      if (lane < 16) {
#pragma unroll
        for (int tt = 0; tt < 16; tt++) Tb[wv][tt][l16] = f2b(Tc[tt]);
      }
    }
    __syncthreads();

    // ---- phase 4: block forward substitution, D = (I+M)^{-1} RHS ----
    {
      short8 a = (short8)(short)0, bT = (short8)(short)0;
      const int arow = wv * 16 + l16;
      if (lg < 2) {
        a = *(const short8*)&Dbf[arow][((lg * 8) ^ ((arow & 7) << 3))];
        bT = *(const short8*)&Tb[0][l16][lg * 8];
      }
      float4v acc0 = {};
      acc0 = MFMA32(a, bT, acc0);
      __syncthreads();
#pragma unroll
      for (int reg = 0; reg < 4; reg++) {
        int v = wv * 16 + lg * 4 + reg;
        Dbf[v][(l16 ^ ((v & 7) << 3))] = f2b(acc0[reg]);
      }
    }
    __syncthreads();
#pragma unroll
    for (int s = 1; s < 4; s++) {
      float4v acc = {};
      const int arow = wv * 16 + l16;
      const int mrow = s * 16 + l16;
#pragma unroll
      for (int j = 0; j < 3; j++) {
        if (j < s) {
          short8 a = (short8)(short)0, bM = (short8)(short)0;
          if (lg < 2) {
            a  = *(const short8*)&Dbf[arow][((j * 16 + lg * 8) ^ ((arow & 7) << 3))];
            bM = *(const short8*)&Mb[mrow][((j * 16 + lg * 8) ^ ((mrow & 7) << 3))];
          }
          acc = MFMA32(a, bM, acc);
        }
      }
#pragma unroll
      for (int reg = 0; reg < 4; reg++) {
        int v = wv * 16 + lg * 4 + reg;
        float rt = b2f(Dbf[v][((s * 16 + l16) ^ ((v & 7) << 3))]);
        rtmp[v][l16] = f2b(rt - acc[reg]);
      }
      __syncthreads();
      short8 a2 = (short8)(short)0, bT = (short8)(short)0;
      if (lg < 2) {
        a2 = *(const short8*)&rtmp[wv * 16 + l16][lg * 8];
        bT = *(const short8*)&Tb[s][l16][lg * 8];
      }
      float4v acc2 = {};
      acc2 = MFMA32(a2, bT, acc2);
      __syncthreads();
#pragma unroll
      for (int reg = 0; reg < 4; reg++) {
        int v = wv * 16 + lg * 4 + reg;
        Dbf[v][((s * 16 + l16) ^ ((v & 7) << 3))] = f2b(acc2[reg]);
      }
      __syncthreads();
    }

    // ---- phase 5: O = diag(gam) Q S0^T + N D ----
    {
      float4v acc[4] = {};
      const int arow = wv * 16 + l16;  // t
      const int asw = (arow & 7) << 3;
#pragma unroll
      for (int kk = 0; kk < 4; kk++) {
        short8 aq = *(const short8*)&Qb[arow][(kk * 32 + lg * 8) ^ asw];
#pragma unroll
        for (int j = 0; j < 4; j++) {
          int brow = j * 16 + l16;  // v
          short8 bs = *(const short8*)&Sb[brow][(kk * 32 + lg * 8) ^ ((brow & 7) << 3)];
          acc[j] = MFMA32(aq, bs, acc[j]);
        }
      }
#pragma unroll
      for (int j = 0; j < 4; j++) {
#pragma unroll
        for (int reg = 0; reg < 4; reg++) {
          int tt = wv * 16 + lg * 4 + reg;
          acc[j][reg] *= gamv[tt];
        }
      }
#pragma unroll
      for (int kk = 0; kk < 2; kk++) {
        short8 an = *(const short8*)&Nb[arow][(kk * 32 + lg * 8) ^ asw];
#pragma unroll
        for (int j = 0; j < 4; j++) {
          int brow = j * 16 + l16;  // v
          short8 bd = *(const short8*)&Dbf[brow][(kk * 32 + lg * 8) ^ ((brow & 7) << 3)];
          acc[j] = MFMA32(an, bd, acc[j]);
        }
      }
      __syncthreads();  // Vt consumed; reuse as obuf
#pragma unroll
      for (int j = 0; j < 4; j++) {
#pragma unroll
        for (int reg = 0; reg < 4; reg++) {
          int tt = wv * 16 + lg * 4 + reg;
          int v = j * 16 + l16;
          Vt[tt][v ^ ((tt & 7) << 3)] = f2b(acc[j][reg]);
        }
      }
    }
    __syncthreads();
    {
      int tt = t >> 2, q4 = t & 3;
      int sw = (tt & 7) << 3;
      unsigned short* yg = y + (size_t)(bS + s0 + tt) * 4096 + h * 128 + half * 64 + q4 * 16;
      short8 o0 = *(const short8*)&Vt[tt][(q4 * 16) ^ sw];
      short8 o1 = *(const short8*)&Vt[tt][(q4 * 16 + 8) ^ sw];
      *(short8*)yg = o0;
      *(short8*)(yg + 8) = o1;
    }

    // ---- phase 6: state update S = gamC * S + D^T Ktt ----
    {
      float gC = gcs[1];
#pragma unroll
      for (int dt = 0; dt < 8; dt++)
#pragma unroll
        for (int reg = 0; reg < 4; reg++) accS[dt][reg] *= gC;
      const int arow = wv * 16 + l16;  // v
      const int asw = (arow & 7) << 3;
#pragma unroll
      for (int kk = 0; kk < 2; kk++) {
        short8 ad = *(const short8*)&Dbf[arow][(kk * 32 + lg * 8) ^ asw];
#pragma unroll
        for (int dt = 0; dt < 8; dt++) {
          int brow = dt * 16 + l16;  // d
          short8 bk = *(const short8*)&Ktt[brow][(kk * 32 + lg * 8) ^ ((brow & 7) << 3)];
          accS[dt] = MFMA32(ad, bk, accS[dt]);
        }
      }
      __syncthreads();
#pragma unroll
      for (int dt = 0; dt < 8; dt++) {
#pragma unroll
        for (int reg = 0; reg < 4; reg++) {
          int v = wv * 16 + lg * 4 + reg;
          int d = dt * 16 + l16;
          Sb[v][d ^ ((v & 7) << 3)] = f2b(accS[dt][reg]);
        }
      }
    }
    __syncthreads();
  }

  // final state writeout (fp32)
#pragma unroll
  for (int dt = 0; dt < 8; dt++) {
#pragma unroll
    for (int reg = 0; reg < 4; reg++) {
      int v = wv * 16 + lg * 4 + reg;
      int d = dt * 16 + l16;
      state_out[((size_t)((b * 32 + h) * 128 + half * 64 + v)) * 128 + d] = accS[dt][reg];
    }
  }
}

// ---- RMSNorm over DV * norm_w * silu(z) -> yn bf16 ----
__global__ __launch_bounds__(256)
void rms_silu(const unsigned short* __restrict__ y, const unsigned short* __restrict__ qkvz,
              const float* __restrict__ nw, unsigned short* __restrict__ yn) {
  int m = blockIdx.x;
  int t = threadIdx.x;
  int head = t >> 3, oct = t & 7;
  int vb = head * 128 + oct * 16;
  const unsigned short* yp = y + (size_t)m * 4096 + vb;
  float yy[16];
  short8 y0 = *(const short8*)yp, y1 = *(const short8*)(yp + 8);
#pragma unroll
  for (int e = 0; e < 8; e++) { yy[e] = b2f((unsigned short)y0[e]); yy[8 + e] = b2f((unsigned short)y1[e]); }
  float ss = 0.f;
#pragma unroll
  for (int e = 0; e < 16; e++) ss += yy[e] * yy[e];
  ss += __shfl_xor(ss, 1); ss += __shfl_xor(ss, 2); ss += __shfl_xor(ss, 4);
  float rinv = rsqrtf(ss * (1.f / 128.f) + 1e-6f);
  const unsigned short* zp = qkvz + (size_t)m * NP + 8192 + vb;
  short8 z0 = *(const short8*)zp, z1 = *(const short8*)(zp + 8);
  short8 o0, o1;
#pragma unroll
  for (int e = 0; e < 8; e++) {
    float z = b2f((unsigned short)z0[e]);
    float v = nw[oct * 16 + e] * yy[e] * rinv * (z / (1.f + expf(-z)));
    o0[e] = (short)f2b(v);
    z = b2f((unsigned short)z1[e]);
    v = nw[oct * 16 + 8 + e] * yy[8 + e] * rinv * (z / (1.f + expf(-z)));
    o1[e] = (short)f2b(v);
  }
  unsigned short* op = yn + (size_t)m * 4096 + vb;
  *(short8*)op = o0;
  *(short8*)(op + 8) = o1;
}

extern "C" void kernel_launch(void* const* d_in, const int* in_sizes, int n_in,
                              void* d_out, int out_size, void* d_ws, size_t ws_size,
                              hipStream_t stream) {
  if (ws_size < WS_NEED) return;  // guard: fail with clean absmax, not a fault

  const float* x     = (const float*)d_in[0];
  const float* Wqkv  = (const float*)d_in[1];
  const float* Wz    = (const float*)d_in[2];
  const float* Wa    = (const float*)d_in[3];
  const float* Wb    = (const float*)d_in[4];
  const float* convw = (const float*)d_in[5];
  const float* Alog  = (const float*)d_in[6];
  const float* dtb   = (const float*)d_in[7];
  const float* nw    = (const float*)d_in[8];
  const float* Wout  = (const float*)d_in[9];

  char* ws = (char*)d_ws;
  unsigned short* qkvz = (unsigned short*)(ws + OFF_QKVZ);
  unsigned short* xb   = (unsigned short*)(ws + OFF_XB);
  unsigned short* wcat = (unsigned short*)(ws + OFF_WCAT);
  unsigned short* qkvs = (unsigned short*)(ws + OFF_QKVS);
  unsigned short* ynb  = (unsigned short*)(ws + OFF_YN);
  unsigned short* wob  = (unsigned short*)(ws + OFF_WOB);
  float* gbuf          = (float*)(ws + OFF_G);
  float* bbuf          = (float*)(ws + OFF_BET);

  float* outp       = (float*)d_out;
  float* conv_state = outp + 8388608;             // B*S*H
  float* state      = outp + 8388608 + 131072;    // + B*CI*KW
  unsigned short* ybuf = (unsigned short*)d_out;  // y bf16 scratch over outp region

  castk<<<8192, 256, 0, stream>>>(x, xb, 2097152);
  prep_wcat<<<25088, 256, 0, stream>>>(Wqkv, Wz, Wa, Wb, wcat);

  // GEMM1: bn-major XCD chunks (each XCD keeps a B-col slab near-L2-resident)
  gemm2x<256, true, unsigned short><<<784, 512, 0, stream>>>(xb, wcat, qkvz, 2048, 16, 49, NP);

  conv_silu_norm<<<256, 1024, 0, stream>>>(qkvz, convw, qkvs);
  conv_state_k<<<512, 256, 0, stream>>>(qkvz, conv_state);
  gb_kernel<<<1024, 256, 0, stream>>>(qkvz, Alog, dtb, gbuf, bbuf);

  scan_chunk<<<256, 256, 0, stream>>>(qkvs, gbuf, bbuf, ybuf, state);

  rms_silu<<<4096, 256, 0, stream>>>(ybuf, qkvz, nw, ynb);
  castk<<<8192, 256, 0, stream>>>(Wout, wob, 2097152);

  // GEMM2: BM=128 -> 256 blocks (all CUs busy), bm-major XCD chunks
  gemm2x<128, false, float><<<256, 512, 0, stream>>>(ynb, wob, outp, 4096, 32, 8, 2048);
}